// Round 2
// 672.996 us; speedup vs baseline: 1.7859x; 1.7859x over previous
//
#include <hip/hip_runtime.h>

// Problem constants (match reference)
#define NUM_USERS   50000
#define NUM_ITEMS   10000
#define NUM_SUPPORT 5
#define INPUT_DIM   512      // K
#define OUTPUT_DIM  500
#define NPAD        512      // padded output-dim stride for XU/XV
#define HIDDEN      100      // OUTPUT_DIM / NUM_SUPPORT
#define NNZ         400000
#define NEDGE       (NUM_SUPPORT * NNZ)     // 2,000,000

// radix-partition parameters
#define CH_E        8192                         // edges per chunk
#define NCHUNK      ((NEDGE + CH_E - 1) / CH_E)  // 245
#define NB_U        ((NUM_SUPPORT * NUM_USERS + 255) / 256)   // 977
#define NB_V        ((NUM_SUPPORT * NUM_ITEMS + 255) / 256)   // 196
#define HISTM_MAX   240000                       // >= NB_U * NCHUNK = 239365

typedef unsigned int u32;
typedef unsigned short ushort_t;
typedef __attribute__((ext_vector_type(4))) float f32x4;
typedef __attribute__((ext_vector_type(8))) short bf16x8;   // 8 bf16 in 4 VGPRs

// async global->LDS, 16B per lane. LDS side must be wave-uniform base + lane*16.
#define GLDS(g, l) __builtin_amdgcn_global_load_lds( \
    (const __attribute__((address_space(1))) unsigned int*)(g), \
    (__attribute__((address_space(3))) unsigned int*)(l), 16, 0, 0)

__device__ inline ushort_t bf16_rne(float f) {
    u32 u = __float_as_uint(f);
    u32 r = (u + 0x7FFFu + ((u >> 16) & 1u)) >> 16;
    return (ushort_t)r;
}
__device__ inline float bf16_lo_f32(u32 w) { return __uint_as_float(w << 16); }
__device__ inline float bf16_hi_f32(u32 w) { return __uint_as_float(w & 0xFFFF0000u); }

// ---------------------------------------------------------------------------
// f32 -> bf16 conversion, 4 elems/thread
// ---------------------------------------------------------------------------
__global__ __launch_bounds__(256) void cvt_bf16(
    const float4* __restrict__ in, ushort4* __restrict__ out, int n4)
{
    int t = blockIdx.x * 256 + threadIdx.x;
    if (t >= n4) return;
    float4 v = in[t];
    ushort4 o;
    o.x = bf16_rne(v.x); o.y = bf16_rne(v.y);
    o.z = bf16_rne(v.z); o.w = bf16_rne(v.w);
    out[t] = o;
}

// WbT[n][k] = W[k][n] (bf16), n padded 500->512 with zeros. 512x512.
__global__ __launch_bounds__(256) void make_WbT(
    const float* __restrict__ W, ushort_t* __restrict__ WbT)
{
    int t = blockIdx.x * 256 + threadIdx.x;
    int n = t >> 9, k = t & 511;
    float v = (n < OUTPUT_DIM) ? W[k * OUTPUT_DIM + n] : 0.f;
    WbT[t] = bf16_rne(v);
}

// ---------------------------------------------------------------------------
// MFMA bf16 GEMM: C[M][512](bf16) = A[M][512](bf16) @ BT[512][512](bf16)^T
// 128x128 tile, BK=32, 256 thr (4 waves, each 64x64 = 4x4 tiles of 16x16x32).
// ---------------------------------------------------------------------------
#define BM 128
#define BN 128
#define BK 32

__global__ __launch_bounds__(256) void gemm_mfma_bf16(
    const ushort_t* __restrict__ A,    // [M][512] bf16
    const ushort_t* __restrict__ BT,   // [512][512] bf16 (BT[n][k])
    ushort_t* __restrict__ C,          // [M][512] bf16
    int M)
{
    const int K = INPUT_DIM;
    __shared__ ushort_t As[BM * BK];   // [m][k], 64B rows
    __shared__ ushort_t Bs[BN * BK];   // [n][k], 64B rows

    const int tid  = threadIdx.x;
    const int wave = tid >> 6;
    const int lane = tid & 63;
    const int quad = lane >> 4;
    const int lr   = lane & 15;
    const int m0 = blockIdx.x * BM;
    const int n0 = blockIdx.y * BN;
    const int wm = (wave >> 1) * 64;
    const int wn = (wave & 1) * 64;

    f32x4 acc[4][4] = {};

    for (int k0 = 0; k0 < K; k0 += BK) {
        #pragma unroll
        for (int h = 0; h < 2; ++h) {
            int o   = tid * 16 + h * 4096;
            int row = o >> 6;
            int byt = o & 63;
            int gr  = m0 + row; if (gr >= M) gr = M - 1;   // clamp (masked at store)
            GLDS((const char*)A + ((long long)gr * K + k0) * 2 + byt, (char*)As + o);
        }
        #pragma unroll
        for (int h = 0; h < 2; ++h) {
            int o   = tid * 16 + h * 4096;
            int row = o >> 6;
            int byt = o & 63;
            GLDS((const char*)BT + ((long long)(n0 + row) * K + k0) * 2 + byt, (char*)Bs + o);
        }
        asm volatile("s_waitcnt vmcnt(0)" ::: "memory");
        __syncthreads();

        bf16x8 af[4], bfr[4];
        #pragma unroll
        for (int tm = 0; tm < 4; ++tm)
            af[tm] = *(const bf16x8*)(As + (wm + tm * 16 + lr) * BK + quad * 8);
        #pragma unroll
        for (int tn = 0; tn < 4; ++tn)
            bfr[tn] = *(const bf16x8*)(Bs + (wn + tn * 16 + lr) * BK + quad * 8);
        #pragma unroll
        for (int tm = 0; tm < 4; ++tm)
            #pragma unroll
            for (int tn = 0; tn < 4; ++tn)
                acc[tm][tn] = __builtin_amdgcn_mfma_f32_16x16x32_bf16(
                    af[tm], bfr[tn], acc[tm][tn], 0, 0, 0);
        __syncthreads();
    }

    // epilogue: C/D layout col=lane&15, row=quad*4+reg
    #pragma unroll
    for (int tm = 0; tm < 4; ++tm) {
        int rbase = m0 + wm + tm * 16 + quad * 4;
        #pragma unroll
        for (int tn = 0; tn < 4; ++tn) {
            int col = n0 + wn + tn * 16 + lr;
            #pragma unroll
            for (int g = 0; g < 4; ++g) {
                int row = rbase + g;
                if (row < M) C[(long long)row * NPAD + col] = bf16_rne(acc[tm][tn][g]);
            }
        }
    }
}

// ---------------------------------------------------------------------------
// Scan helpers (exclusive scan over u32 arrays, n <= 262144)
// ---------------------------------------------------------------------------
__global__ __launch_bounds__(256) void scan1(u32* __restrict__ data, int n,
                                             u32* __restrict__ partials)
{
    __shared__ u32 sh[256];
    int t = threadIdx.x;
    int base = blockIdx.x * 1024 + t * 4;
    u32 x[4];
    #pragma unroll
    for (int k = 0; k < 4; ++k) {
        int idx = base + k;
        x[k] = (idx < n) ? data[idx] : 0u;
    }
    u32 tsum = x[0] + x[1] + x[2] + x[3];
    sh[t] = tsum;
    __syncthreads();
    for (int off = 1; off < 256; off <<= 1) {
        u32 v = (t >= off) ? sh[t - off] : 0u;
        __syncthreads();
        sh[t] += v;
        __syncthreads();
    }
    u32 run = (t > 0) ? sh[t - 1] : 0u;
    if (t == 255) partials[blockIdx.x] = sh[255];
    #pragma unroll
    for (int k = 0; k < 4; ++k) {
        int idx = base + k;
        if (idx < n) data[idx] = run;
        run += x[k];
    }
}

__global__ __launch_bounds__(256) void scan_partials(u32* __restrict__ partials, int n)
{
    __shared__ u32 sh[256];
    int t = threadIdx.x;
    u32 x = (t < n) ? partials[t] : 0u;
    sh[t] = x;
    __syncthreads();
    for (int off = 1; off < 256; off <<= 1) {
        u32 v = (t >= off) ? sh[t - off] : 0u;
        __syncthreads();
        sh[t] += v;
        __syncthreads();
    }
    if (t < n) partials[t] = (t > 0) ? sh[t - 1] : 0u;
}

__global__ __launch_bounds__(256) void scan_add(u32* __restrict__ data, int n,
                                                const u32* __restrict__ partials)
{
    int idx = blockIdx.x * 256 + threadIdx.x;
    if (idx < n) data[idx] += partials[idx >> 10];
}

// ---------------------------------------------------------------------------
// Chunked radix partition (replaces global-atomic hist+sort).
// key = support * NROWS + idx; bucket = key >> 8 (256 keys/bucket).
// Phase A: per-chunk LDS histogram -> histm[bucket][chunk]
// (global exclusive scan of histm in bucket-major order)
// Phase B: per-chunk LDS cursors, append 8B payload (val, key<<GSHIFT|gidx)
//          into block-private bucket runs -> line-coalescing writes.
// Phase C: per-bucket key count + LDS scan -> writes row_ptr AND final
//          (val, gidx) perm entries into the bucket's contiguous window.
// No global atomics anywhere; no 64B-line write amplification.
// ---------------------------------------------------------------------------
template<int NROWS>
__global__ __launch_bounds__(256) void chunk_hist(
    const int* __restrict__ keyidx, u32* __restrict__ histm)
{
    constexpr int NKEY = NUM_SUPPORT * NROWS;
    constexpr int NB = (NKEY + 255) / 256;
    __shared__ u32 hist[NB];
    const int tid = threadIdx.x;
    const int c = blockIdx.x;
    for (int b = tid; b < NB; b += 256) hist[b] = 0u;
    __syncthreads();
    int base = c * CH_E;
    int end = base + CH_E; if (end > NEDGE) end = NEDGE;
    for (int e = base + tid; e < end; e += 256) {
        unsigned i = (unsigned)e / (unsigned)NNZ;
        u32 key = i * (u32)NROWS + (u32)keyidx[e];
        atomicAdd(&hist[key >> 8], 1u);
    }
    __syncthreads();
    for (int b = tid; b < NB; b += 256) histm[b * NCHUNK + c] = hist[b];
}

template<int NROWS, int GSHIFT>
__global__ __launch_bounds__(256) void partition_edges(
    const int* __restrict__ keyidx, const int* __restrict__ gidx,
    const float* __restrict__ vals,
    const u32* __restrict__ histm, uint2* __restrict__ buf)
{
    constexpr int NKEY = NUM_SUPPORT * NROWS;
    constexpr int NB = (NKEY + 255) / 256;
    __shared__ u32 cur[NB];
    const int tid = threadIdx.x;
    const int c = blockIdx.x;
    for (int b = tid; b < NB; b += 256) cur[b] = histm[b * NCHUNK + c];
    __syncthreads();
    int base = c * CH_E;
    int end = base + CH_E; if (end > NEDGE) end = NEDGE;
    for (int e = base + tid; e < end; e += 256) {
        unsigned i = (unsigned)e / (unsigned)NNZ;
        u32 key = i * (u32)NROWS + (u32)keyidx[e];
        u32 p = atomicAdd(&cur[key >> 8], 1u);
        uint2 pay;
        pay.x = __float_as_uint(vals[e]);
        pay.y = (key << GSHIFT) | (u32)gidx[e];
        buf[p] = pay;
    }
}

template<int NROWS, int GSHIFT>
__global__ __launch_bounds__(256) void bucket_scatter(
    const uint2* __restrict__ buf, const u32* __restrict__ histm,
    u32* __restrict__ ptr, uint2* __restrict__ perm)
{
    constexpr int NKEY = NUM_SUPPORT * NROWS;
    constexpr int NB = (NKEY + 255) / 256;
    __shared__ u32 cnt[256];
    __shared__ u32 scn[256];
    const int tid = threadIdx.x;
    const int b = blockIdx.x;
    const u32 key0 = (u32)b << 8;
    const u32 start = histm[b * NCHUNK];
    const u32 bend  = (b + 1 < NB) ? histm[(b + 1) * NCHUNK] : (u32)NEDGE;
    cnt[tid] = 0u;
    __syncthreads();
    for (u32 j = start + tid; j < bend; j += 256) {
        u32 key = buf[j].y >> GSHIFT;
        atomicAdd(&cnt[key - key0], 1u);
    }
    __syncthreads();
    scn[tid] = cnt[tid];
    __syncthreads();
    for (int off = 1; off < 256; off <<= 1) {
        u32 v = (tid >= off) ? scn[tid - off] : 0u;
        __syncthreads();
        scn[tid] += v;
        __syncthreads();
    }
    u32 myoff = start + scn[tid] - cnt[tid];   // exclusive within bucket
    if (key0 + (u32)tid < (u32)NKEY) ptr[key0 + tid] = myoff;
    __syncthreads();
    cnt[tid] = myoff;                          // becomes running cursor
    __syncthreads();
    for (u32 j = start + tid; j < bend; j += 256) {
        uint2 q = buf[j];
        u32 key = q.y >> GSHIFT;
        u32 p = atomicAdd(&cnt[key - key0], 1u);
        uint2 out;
        out.x = q.x;
        out.y = q.y & ((1u << GSHIFT) - 1u);
        perm[p] = out;
    }
}

__global__ void set_sentinels(u32* __restrict__ a, u32* __restrict__ b)
{
    a[0] = (u32)NEDGE;
    b[0] = (u32)NEDGE;
}

// ---------------------------------------------------------------------------
// Permutation SpMM: one wave per (support, output-row).
// perm entries embed (val, gidx) -> no random vals/gidx reads.
// lanes 0..49 each own 2 cols; gathers are bf16 (u32 = 2 elems). Fused ReLU.
// ---------------------------------------------------------------------------
__global__ __launch_bounds__(256) void spmm_perm(
    const u32* __restrict__ ptr,      // [NSUP*nrows + 1] CSR offsets
    const uint2* __restrict__ perm,   // [NEDGE] (val_bits, gather_idx)
    const ushort_t* __restrict__ X,   // [nsrc][NPAD] bf16
    float* __restrict__ Z,            // [nrows][OUTPUT_DIM] f32
    int nrows)
{
    int wv   = (int)((blockIdx.x * 256u + threadIdx.x) >> 6);
    int lane = threadIdx.x & 63;
    if (wv >= NUM_SUPPORT * nrows) return;
    int i = wv / nrows;
    int r = wv % nrows;
    const int cbase = i * HIDDEN;

    u32 s = ptr[wv], e = ptr[wv + 1];
    float ax = 0.f, ay = 0.f;
    u32 k = s;
    // unroll-2 so the two edges' random gathers overlap
    for (; k + 1 < e; k += 2) {
        uint2 q0 = perm[k], q1 = perm[k + 1];
        float v0 = __uint_as_float(q0.x), v1 = __uint_as_float(q1.x);
        const ushort_t* x0 = X + (long long)q0.y * NPAD + cbase;
        const ushort_t* x1 = X + (long long)q1.y * NPAD + cbase;
        if (lane < 50) {
            u32 w0 = *(const u32*)(x0 + 2 * lane);
            u32 w1 = *(const u32*)(x1 + 2 * lane);
            ax += v0 * bf16_lo_f32(w0) + v1 * bf16_lo_f32(w1);
            ay += v0 * bf16_hi_f32(w0) + v1 * bf16_hi_f32(w1);
        }
    }
    if (k < e) {
        uint2 q0 = perm[k];
        float v0 = __uint_as_float(q0.x);
        const ushort_t* x0 = X + (long long)q0.y * NPAD + cbase;
        if (lane < 50) {
            u32 w0 = *(const u32*)(x0 + 2 * lane);
            ax += v0 * bf16_lo_f32(w0);
            ay += v0 * bf16_hi_f32(w0);
        }
    }
    if (lane < 50) {
        float2 o;
        o.x = ax > 0.f ? ax : 0.f;
        o.y = ay > 0.f ? ay : 0.f;
        *(float2*)(Z + (long long)r * OUTPUT_DIM + cbase + 2 * lane) = o;
    }
}

// ---------------------------------------------------------------------------
// Fallback path: f32 GEMM + COO atomic scatter (only if ws too small)
// ---------------------------------------------------------------------------
#define TM 64
#define TN 64
#define TK 16

__global__ __launch_bounds__(256) void gemm_f32(
    const float* __restrict__ A, const float* __restrict__ B,
    float* __restrict__ C, int M, int N, int K, int ldc)
{
    __shared__ float Asl[TK][TM + 4];
    __shared__ float Bsl[TK][TN + 4];
    const int tid = threadIdx.x;
    const int tx  = tid & 15;
    const int ty  = tid >> 4;
    const int row0 = blockIdx.x * TM;
    const int col0 = blockIdx.y * TN;
    float acc[4][4] = {};
    for (int k0 = 0; k0 < K; k0 += TK) {
        #pragma unroll
        for (int it = 0; it < (TM * TK) / 256; ++it) {
            int idx = tid + it * 256;
            int m = idx >> 4, kk = idx & 15, gr = row0 + m;
            Asl[kk][m] = (gr < M) ? A[(long long)gr * K + (k0 + kk)] : 0.f;
        }
        #pragma unroll
        for (int it = 0; it < (TK * TN) / 256; ++it) {
            int idx = tid + it * 256;
            int kk = idx >> 6, n = idx & 63, gc = col0 + n;
            Bsl[kk][n] = (gc < N) ? B[(long long)(k0 + kk) * N + gc] : 0.f;
        }
        __syncthreads();
        #pragma unroll
        for (int kk = 0; kk < TK; ++kk) {
            float a[4], b[4];
            #pragma unroll
            for (int u = 0; u < 4; ++u) a[u] = Asl[kk][ty * 4 + u];
            #pragma unroll
            for (int v = 0; v < 4; ++v) b[v] = Bsl[kk][tx * 4 + v];
            #pragma unroll
            for (int u = 0; u < 4; ++u)
                #pragma unroll
                for (int v = 0; v < 4; ++v)
                    acc[u][v] += a[u] * b[v];
        }
        __syncthreads();
    }
    #pragma unroll
    for (int u = 0; u < 4; ++u) {
        int gr = row0 + ty * 4 + u;
        if (gr >= M) continue;
        #pragma unroll
        for (int v = 0; v < 4; ++v) {
            int gc = col0 + tx * 4 + v;
            if (gc < N) C[(long long)gr * ldc + gc] = acc[u][v];
        }
    }
}

__global__ __launch_bounds__(256) void scatter_edges(
    const float* __restrict__ sup_vals,
    const int*   __restrict__ sup_rows,
    const int*   __restrict__ sup_cols,
    const float* __restrict__ XU, const float* __restrict__ XV,
    float* __restrict__ z_u, float* __restrict__ z_v)
{
    const unsigned t = blockIdx.x * 256u + threadIdx.x;
    const unsigned total = (unsigned)NEDGE * HIDDEN;
    if (t >= total) return;
    const unsigned j  = t % HIDDEN;
    const unsigned eg = t / HIDDEN;
    const unsigned i  = eg / NNZ;
    const float val = sup_vals[eg];
    const int   r   = sup_rows[eg];
    const int   c   = sup_cols[eg];
    const int   colOff = i * HIDDEN + j;
    atomicAdd(&z_u[(long long)r * OUTPUT_DIM + colOff],
              val * XV[(long long)c * NPAD + colOff]);
    atomicAdd(&z_v[(long long)c * OUTPUT_DIM + colOff],
              val * XU[(long long)r * NPAD + colOff]);
}

__global__ __launch_bounds__(256) void relu_inplace(float4* __restrict__ p, int n4)
{
    int t = blockIdx.x * 256 + threadIdx.x;
    if (t >= n4) return;
    float4 v = p[t];
    v.x = v.x > 0.f ? v.x : 0.f;
    v.y = v.y > 0.f ? v.y : 0.f;
    v.z = v.z > 0.f ? v.z : 0.f;
    v.w = v.w > 0.f ? v.w : 0.f;
    p[t] = v;
}

extern "C" void kernel_launch(void* const* d_in, const int* in_sizes, int n_in,
                              void* d_out, int out_size, void* d_ws, size_t ws_size,
                              hipStream_t stream)
{
    const float* x_u      = (const float*)d_in[0];
    const float* x_v      = (const float*)d_in[1];
    const float* W        = (const float*)d_in[2];
    const float* sup_vals = (const float*)d_in[3];
    const int*   sup_rows = (const int*)d_in[4];
    const int*   sup_cols = (const int*)d_in[5];

    float* z_u = (float*)d_out;
    float* z_v = z_u + (long long)NUM_USERS * OUTPUT_DIM;

    const long long NU = (long long)NUM_USERS * NPAD;   // 25.6M elems
    const long long NV = (long long)NUM_ITEMS * NPAD;   //  5.12M elems
    const int NRU = NUM_SUPPORT * NUM_USERS;  // 250000 keys (u side)
    const int NRV = NUM_SUPPORT * NUM_ITEMS;  //  50000 keys (v side)

    // ---- full-path workspace layout ----
    ushort_t* XUb   = (ushort_t*)d_ws;        // gemm out, bf16 [50000][512]
    ushort_t* XVb   = XUb + NU;               // gemm out, bf16 [10000][512]
    ushort_t* xu_in = XVb + NV;               // bf16(x_u); reused as scratch post-GEMM
    ushort_t* xv_in = xu_in + NU;             // bf16(x_v)
    ushort_t* WbT   = xv_in + NV;             // bf16 W^T padded [512][512]
    u32* row_ptr_u  = (u32*)(WbT + 512 * 512);     // [NRU+1]
    u32* col_ptr_v  = row_ptr_u + (NRU + 1);       // [NRV+1]
    u32* partials   = col_ptr_v + (NRV + 1);       // [1024]
    size_t need_full = ((char*)(partials + 1024)) - ((char*)d_ws);

    // scratch aliases inside xu_in (only used AFTER both GEMMs consumed it):
    // buf(16MB) + histm(0.96MB) + perm_u(16MB) + perm_v(16MB) = 48.96MB <= 51.2MB
    uint2* buf    = (uint2*)xu_in;            // [NEDGE] phase-B staging
    u32*   histm  = (u32*)(buf + NEDGE);      // [HISTM_MAX] bucket x chunk matrix
    uint2* perm_u = (uint2*)(histm + HISTM_MAX);   // [NEDGE] final (val,gidx)
    uint2* perm_v = perm_u + NEDGE;                // [NEDGE]

    dim3 blk(256);

    if (ws_size >= need_full) {
        // ---- dense projections (bf16 MFMA) ----
        cvt_bf16<<<(int)((NU / 4 + 255) / 256), blk, 0, stream>>>(
            (const float4*)x_u, (ushort4*)xu_in, (int)(NU / 4));
        cvt_bf16<<<(int)((NV / 4 + 255) / 256), blk, 0, stream>>>(
            (const float4*)x_v, (ushort4*)xv_in, (int)(NV / 4));
        make_WbT<<<(512 * 512) / 256, blk, 0, stream>>>(W, WbT);
        gemm_mfma_bf16<<<dim3((NUM_USERS + BM - 1) / BM, NPAD / BN), blk, 0, stream>>>(
            xu_in, WbT, XUb, NUM_USERS);
        gemm_mfma_bf16<<<dim3((NUM_ITEMS + BM - 1) / BM, NPAD / BN), blk, 0, stream>>>(
            xv_in, WbT, XVb, NUM_ITEMS);

        // xu_in is now dead -> buf/histm/perm_u/perm_v scratch is live.
        auto scan_u32 = [&](u32* data, int n) {
            int nb = (n + 1023) / 1024;
            scan1<<<nb, blk, 0, stream>>>(data, n, partials);
            scan_partials<<<1, blk, 0, stream>>>(partials, nb);
            scan_add<<<(n + 255) / 256, blk, 0, stream>>>(data, n, partials);
        };

        // ---- u-side partition: key = i*NUM_USERS + row, gidx = col (14 bits) ----
        chunk_hist<NUM_USERS><<<NCHUNK, blk, 0, stream>>>(sup_rows, histm);
        scan_u32(histm, NB_U * NCHUNK);                       // 239365 <= 262144
        partition_edges<NUM_USERS, 14><<<NCHUNK, blk, 0, stream>>>(
            sup_rows, sup_cols, sup_vals, histm, buf);
        bucket_scatter<NUM_USERS, 14><<<NB_U, blk, 0, stream>>>(
            buf, histm, row_ptr_u, perm_u);

        // ---- v-side partition: key = i*NUM_ITEMS + col, gidx = row (16 bits) ----
        chunk_hist<NUM_ITEMS><<<NCHUNK, blk, 0, stream>>>(sup_cols, histm);
        scan_u32(histm, NB_V * NCHUNK);                       // 48020
        partition_edges<NUM_ITEMS, 16><<<NCHUNK, blk, 0, stream>>>(
            sup_cols, sup_rows, sup_vals, histm, buf);
        bucket_scatter<NUM_ITEMS, 16><<<NB_V, blk, 0, stream>>>(
            buf, histm, col_ptr_v, perm_v);

        set_sentinels<<<1, 1, 0, stream>>>(row_ptr_u + NRU, col_ptr_v + NRV);

        // ---- SpMM (fused ReLU) ----
        spmm_perm<<<(NRU * 64 + 255) / 256, blk, 0, stream>>>(
            row_ptr_u, perm_u, XVb, z_u, NUM_USERS);
        spmm_perm<<<(NRV * 64 + 255) / 256, blk, 0, stream>>>(
            col_ptr_v, perm_v, XUb, z_v, NUM_ITEMS);
    } else {
        // ---- fallback: f32 GEMM + atomic scatter ----
        float* XU = (float*)d_ws;
        float* XV = XU + NU;
        gemm_f32<<<dim3((NUM_USERS + TM - 1) / TM, (OUTPUT_DIM + TN - 1) / TN),
                   blk, 0, stream>>>(x_u, W, XU, NUM_USERS, OUTPUT_DIM, INPUT_DIM, NPAD);
        gemm_f32<<<dim3((NUM_ITEMS + TM - 1) / TM, (OUTPUT_DIM + TN - 1) / TN),
                   blk, 0, stream>>>(x_v, W, XV, NUM_ITEMS, OUTPUT_DIM, INPUT_DIM, NPAD);
        hipMemsetAsync(d_out, 0, (size_t)out_size * sizeof(float), stream);
        unsigned total = (unsigned)NEDGE * HIDDEN;
        scatter_edges<<<(total + 255u) / 256u, blk, 0, stream>>>(
            sup_vals, sup_rows, sup_cols, XU, XV, z_u, z_v);
        int n4 = out_size / 4;
        relu_inplace<<<(n4 + 255) / 256, blk, 0, stream>>>((float4*)d_out, n4);
    }
}

// Round 3
// 581.154 us; speedup vs baseline: 2.0681x; 1.1580x over previous
//
#include <hip/hip_runtime.h>

// Problem constants (match reference)
#define NUM_USERS   50000
#define NUM_ITEMS   10000
#define NUM_SUPPORT 5
#define INPUT_DIM   512      // K
#define OUTPUT_DIM  500
#define NPAD        512      // padded output-dim stride (fallback path only)
#define HIDDEN      100      // OUTPUT_DIM / NUM_SUPPORT
#define HPAD        128      // packed per-support row: 100 bf16 padded to 128 (256B)
#define NNZ         400000
#define NEDGE       (NUM_SUPPORT * NNZ)     // 2,000,000

// radix-partition parameters
#define CH_E        8192                         // edges per chunk
#define NCHUNK      ((NEDGE + CH_E - 1) / CH_E)  // 245
#define NB_U        ((NUM_SUPPORT * NUM_USERS + 255) / 256)   // 977
#define NB_V        ((NUM_SUPPORT * NUM_ITEMS + 255) / 256)   // 196
#define HISTM_MAX   240000                       // >= NB_U * NCHUNK = 239365

typedef unsigned int u32;
typedef unsigned short ushort_t;
typedef __attribute__((ext_vector_type(4))) float f32x4;
typedef __attribute__((ext_vector_type(8))) short bf16x8;   // 8 bf16 in 4 VGPRs

// async global->LDS, 16B per lane. LDS side must be wave-uniform base + lane*16.
#define GLDS(g, l) __builtin_amdgcn_global_load_lds( \
    (const __attribute__((address_space(1))) unsigned int*)(g), \
    (__attribute__((address_space(3))) unsigned int*)(l), 16, 0, 0)

__device__ inline ushort_t bf16_rne(float f) {
    u32 u = __float_as_uint(f);
    u32 r = (u + 0x7FFFu + ((u >> 16) & 1u)) >> 16;
    return (ushort_t)r;
}
__device__ inline float bf16_lo_f32(u32 w) { return __uint_as_float(w << 16); }
__device__ inline float bf16_hi_f32(u32 w) { return __uint_as_float(w & 0xFFFF0000u); }

// ---------------------------------------------------------------------------
// f32 -> bf16 conversion, 4 elems/thread
// ---------------------------------------------------------------------------
__global__ __launch_bounds__(256) void cvt_bf16(
    const float4* __restrict__ in, ushort4* __restrict__ out, int n4)
{
    int t = blockIdx.x * 256 + threadIdx.x;
    if (t >= n4) return;
    float4 v = in[t];
    ushort4 o;
    o.x = bf16_rne(v.x); o.y = bf16_rne(v.y);
    o.z = bf16_rne(v.z); o.w = bf16_rne(v.w);
    out[t] = o;
}

// WbT[n][k] = W[k][n] (bf16), n padded 500->512 with zeros. 512x512.
__global__ __launch_bounds__(256) void make_WbT(
    const float* __restrict__ W, ushort_t* __restrict__ WbT)
{
    int t = blockIdx.x * 256 + threadIdx.x;
    int n = t >> 9, k = t & 511;
    float v = (n < OUTPUT_DIM) ? W[k * OUTPUT_DIM + n] : 0.f;
    WbT[t] = bf16_rne(v);
}

// ---------------------------------------------------------------------------
// MFMA bf16 GEMM: Xp[seg][M][128](bf16) = relu-less pack of A @ BT^T
// 128x128 tile, BK=32, 256 thr (4 waves, each 64x64 = 4x4 tiles of 16x16x32).
// Epilogue writes support-major packed layout: col c -> seg=c/100, off=c%100.
// Pad cols 100..127 of each packed row are never written (never stored later).
// ---------------------------------------------------------------------------
#define BM 128
#define BN 128
#define BK 32

__global__ __launch_bounds__(256) void gemm_mfma_bf16(
    const ushort_t* __restrict__ A,    // [M][512] bf16
    const ushort_t* __restrict__ BT,   // [512][512] bf16 (BT[n][k])
    ushort_t* __restrict__ Xp,         // [5][M][HPAD] bf16 packed
    int M)
{
    const int K = INPUT_DIM;
    __shared__ ushort_t As[BM * BK];   // [m][k], 64B rows
    __shared__ ushort_t Bs[BN * BK];   // [n][k], 64B rows

    const int tid  = threadIdx.x;
    const int wave = tid >> 6;
    const int lane = tid & 63;
    const int quad = lane >> 4;
    const int lr   = lane & 15;
    const int m0 = blockIdx.x * BM;
    const int n0 = blockIdx.y * BN;
    const int wm = (wave >> 1) * 64;
    const int wn = (wave & 1) * 64;

    f32x4 acc[4][4] = {};

    for (int k0 = 0; k0 < K; k0 += BK) {
        #pragma unroll
        for (int h = 0; h < 2; ++h) {
            int o   = tid * 16 + h * 4096;
            int row = o >> 6;
            int byt = o & 63;
            int gr  = m0 + row; if (gr >= M) gr = M - 1;   // clamp (masked at store)
            GLDS((const char*)A + ((long long)gr * K + k0) * 2 + byt, (char*)As + o);
        }
        #pragma unroll
        for (int h = 0; h < 2; ++h) {
            int o   = tid * 16 + h * 4096;
            int row = o >> 6;
            int byt = o & 63;
            GLDS((const char*)BT + ((long long)(n0 + row) * K + k0) * 2 + byt, (char*)Bs + o);
        }
        asm volatile("s_waitcnt vmcnt(0)" ::: "memory");
        __syncthreads();

        bf16x8 af[4], bfr[4];
        #pragma unroll
        for (int tm = 0; tm < 4; ++tm)
            af[tm] = *(const bf16x8*)(As + (wm + tm * 16 + lr) * BK + quad * 8);
        #pragma unroll
        for (int tn = 0; tn < 4; ++tn)
            bfr[tn] = *(const bf16x8*)(Bs + (wn + tn * 16 + lr) * BK + quad * 8);
        #pragma unroll
        for (int tm = 0; tm < 4; ++tm)
            #pragma unroll
            for (int tn = 0; tn < 4; ++tn)
                acc[tm][tn] = __builtin_amdgcn_mfma_f32_16x16x32_bf16(
                    af[tm], bfr[tn], acc[tm][tn], 0, 0, 0);
        __syncthreads();
    }

    // epilogue: C/D layout col=lane&15, row=quad*4+reg; scatter into packed Xp
    #pragma unroll
    for (int tm = 0; tm < 4; ++tm) {
        int rbase = m0 + wm + tm * 16 + quad * 4;
        #pragma unroll
        for (int tn = 0; tn < 4; ++tn) {
            int col = n0 + wn + tn * 16 + lr;
            if (col >= OUTPUT_DIM) continue;
            int seg = col / HIDDEN;             // const-div -> magic mul
            int off = col - seg * HIDDEN;
            ushort_t* dst = Xp + (long long)seg * M * HPAD + off;
            #pragma unroll
            for (int g = 0; g < 4; ++g) {
                int row = rbase + g;
                if (row < M) dst[(long long)row * HPAD] = bf16_rne(acc[tm][tn][g]);
            }
        }
    }
}

// ---------------------------------------------------------------------------
// Scan helpers (exclusive scan over u32 arrays, n <= 262144)
// ---------------------------------------------------------------------------
__global__ __launch_bounds__(256) void scan1(u32* __restrict__ data, int n,
                                             u32* __restrict__ partials)
{
    __shared__ u32 sh[256];
    int t = threadIdx.x;
    int base = blockIdx.x * 1024 + t * 4;
    u32 x[4];
    #pragma unroll
    for (int k = 0; k < 4; ++k) {
        int idx = base + k;
        x[k] = (idx < n) ? data[idx] : 0u;
    }
    u32 tsum = x[0] + x[1] + x[2] + x[3];
    sh[t] = tsum;
    __syncthreads();
    for (int off = 1; off < 256; off <<= 1) {
        u32 v = (t >= off) ? sh[t - off] : 0u;
        __syncthreads();
        sh[t] += v;
        __syncthreads();
    }
    u32 run = (t > 0) ? sh[t - 1] : 0u;
    if (t == 255) partials[blockIdx.x] = sh[255];
    #pragma unroll
    for (int k = 0; k < 4; ++k) {
        int idx = base + k;
        if (idx < n) data[idx] = run;
        run += x[k];
    }
}

__global__ __launch_bounds__(256) void scan_partials(u32* __restrict__ partials, int n)
{
    __shared__ u32 sh[256];
    int t = threadIdx.x;
    u32 x = (t < n) ? partials[t] : 0u;
    sh[t] = x;
    __syncthreads();
    for (int off = 1; off < 256; off <<= 1) {
        u32 v = (t >= off) ? sh[t - off] : 0u;
        __syncthreads();
        sh[t] += v;
        __syncthreads();
    }
    if (t < n) partials[t] = (t > 0) ? sh[t - 1] : 0u;
}

__global__ __launch_bounds__(256) void scan_add(u32* __restrict__ data, int n,
                                                const u32* __restrict__ partials)
{
    int idx = blockIdx.x * 256 + threadIdx.x;
    if (idx < n) data[idx] += partials[idx >> 10];
}

// ---------------------------------------------------------------------------
// Chunked radix partition (no global atomics, no line-amplified scatter).
// ---------------------------------------------------------------------------
template<int NROWS>
__global__ __launch_bounds__(256) void chunk_hist(
    const int* __restrict__ keyidx, u32* __restrict__ histm)
{
    constexpr int NKEY = NUM_SUPPORT * NROWS;
    constexpr int NB = (NKEY + 255) / 256;
    __shared__ u32 hist[NB];
    const int tid = threadIdx.x;
    const int c = blockIdx.x;
    for (int b = tid; b < NB; b += 256) hist[b] = 0u;
    __syncthreads();
    int base = c * CH_E;
    int end = base + CH_E; if (end > NEDGE) end = NEDGE;
    for (int e = base + tid; e < end; e += 256) {
        unsigned i = (unsigned)e / (unsigned)NNZ;
        u32 key = i * (u32)NROWS + (u32)keyidx[e];
        atomicAdd(&hist[key >> 8], 1u);
    }
    __syncthreads();
    for (int b = tid; b < NB; b += 256) histm[b * NCHUNK + c] = hist[b];
}

template<int NROWS, int GSHIFT>
__global__ __launch_bounds__(256) void partition_edges(
    const int* __restrict__ keyidx, const int* __restrict__ gidx,
    const float* __restrict__ vals,
    const u32* __restrict__ histm, uint2* __restrict__ buf)
{
    constexpr int NKEY = NUM_SUPPORT * NROWS;
    constexpr int NB = (NKEY + 255) / 256;
    __shared__ u32 cur[NB];
    const int tid = threadIdx.x;
    const int c = blockIdx.x;
    for (int b = tid; b < NB; b += 256) cur[b] = histm[b * NCHUNK + c];
    __syncthreads();
    int base = c * CH_E;
    int end = base + CH_E; if (end > NEDGE) end = NEDGE;
    for (int e = base + tid; e < end; e += 256) {
        unsigned i = (unsigned)e / (unsigned)NNZ;
        u32 key = i * (u32)NROWS + (u32)keyidx[e];
        u32 p = atomicAdd(&cur[key >> 8], 1u);
        uint2 pay;
        pay.x = __float_as_uint(vals[e]);
        pay.y = (key << GSHIFT) | (u32)gidx[e];
        buf[p] = pay;
    }
}

template<int NROWS, int GSHIFT>
__global__ __launch_bounds__(256) void bucket_scatter(
    const uint2* __restrict__ buf, const u32* __restrict__ histm,
    u32* __restrict__ ptr, uint2* __restrict__ perm)
{
    constexpr int NKEY = NUM_SUPPORT * NROWS;
    constexpr int NB = (NKEY + 255) / 256;
    __shared__ u32 cnt[256];
    __shared__ u32 scn[256];
    const int tid = threadIdx.x;
    const int b = blockIdx.x;
    const u32 key0 = (u32)b << 8;
    const u32 start = histm[b * NCHUNK];
    const u32 bend  = (b + 1 < NB) ? histm[(b + 1) * NCHUNK] : (u32)NEDGE;
    cnt[tid] = 0u;
    __syncthreads();
    for (u32 j = start + tid; j < bend; j += 256) {
        u32 key = buf[j].y >> GSHIFT;
        atomicAdd(&cnt[key - key0], 1u);
    }
    __syncthreads();
    scn[tid] = cnt[tid];
    __syncthreads();
    for (int off = 1; off < 256; off <<= 1) {
        u32 v = (tid >= off) ? scn[tid - off] : 0u;
        __syncthreads();
        scn[tid] += v;
        __syncthreads();
    }
    u32 myoff = start + scn[tid] - cnt[tid];   // exclusive within bucket
    if (key0 + (u32)tid < (u32)NKEY) ptr[key0 + tid] = myoff;
    __syncthreads();
    cnt[tid] = myoff;                          // becomes running cursor
    __syncthreads();
    for (u32 j = start + tid; j < bend; j += 256) {
        uint2 q = buf[j];
        u32 key = q.y >> GSHIFT;
        u32 p = atomicAdd(&cnt[key - key0], 1u);
        uint2 out;
        out.x = q.x;
        out.y = q.y & ((1u << GSHIFT) - 1u);
        perm[p] = out;
    }
}

__global__ void set_sentinels(u32* __restrict__ a, u32* __restrict__ b)
{
    a[0] = (u32)NEDGE;
    b[0] = (u32)NEDGE;
}

// ---------------------------------------------------------------------------
// Packed SpMM: one wave per (support, output-row); 4 lane-groups of 16, each
// group owns one edge; each lane gathers 16B (8 bf16 cols) of the 256B packed
// row. Unroll-2 -> 8 gathers in flight/wave. shfl_xor(16,32) merges groups.
// Fused ReLU; lanes 0..12 write the 100 f32 as aligned float4s.
// ---------------------------------------------------------------------------
template<int NROWS>
__global__ __launch_bounds__(256) void spmm_pack(
    const u32* __restrict__ ptr,      // [5*NROWS + 1] CSR offsets
    const uint2* __restrict__ perm,   // [NEDGE] (val_bits, gather_idx)
    const ushort_t* __restrict__ Xp,  // [5][nsrc][HPAD] bf16 packed
    float* __restrict__ Z,            // [NROWS][OUTPUT_DIM] f32
    int nsrc)
{
    int wv = (int)((blockIdx.x * 256u + threadIdx.x) >> 6);
    wv = __builtin_amdgcn_readfirstlane(wv);
    int lane = threadIdx.x & 63;
    if (wv >= NUM_SUPPORT * NROWS) return;
    int i = wv / NROWS;
    int r = wv - i * NROWS;
    const int g  = lane >> 4;     // edge group 0..3
    const int sl = lane & 15;     // 8 bf16 cols per sub-lane

    const ushort_t* Xs = Xp + (long long)i * nsrc * HPAD + sl * 8;

    u32 s = ptr[wv], e = ptr[wv + 1];
    float a0 = 0.f, a1 = 0.f, a2 = 0.f, a3 = 0.f;
    float a4 = 0.f, a5 = 0.f, a6 = 0.f, a7 = 0.f;
    u32 k = s + g;
    for (; k + 4 < e; k += 8) {
        uint2 q0 = perm[k], q1 = perm[k + 4];
        float v0 = __uint_as_float(q0.x), v1 = __uint_as_float(q1.x);
        uint4 w0 = *(const uint4*)(Xs + ((long long)q0.y << 7));
        uint4 w1 = *(const uint4*)(Xs + ((long long)q1.y << 7));
        a0 += v0 * bf16_lo_f32(w0.x) + v1 * bf16_lo_f32(w1.x);
        a1 += v0 * bf16_hi_f32(w0.x) + v1 * bf16_hi_f32(w1.x);
        a2 += v0 * bf16_lo_f32(w0.y) + v1 * bf16_lo_f32(w1.y);
        a3 += v0 * bf16_hi_f32(w0.y) + v1 * bf16_hi_f32(w1.y);
        a4 += v0 * bf16_lo_f32(w0.z) + v1 * bf16_lo_f32(w1.z);
        a5 += v0 * bf16_hi_f32(w0.z) + v1 * bf16_hi_f32(w1.z);
        a6 += v0 * bf16_lo_f32(w0.w) + v1 * bf16_lo_f32(w1.w);
        a7 += v0 * bf16_hi_f32(w0.w) + v1 * bf16_hi_f32(w1.w);
    }
    if (k < e) {
        uint2 q0 = perm[k];
        float v0 = __uint_as_float(q0.x);
        uint4 w0 = *(const uint4*)(Xs + ((long long)q0.y << 7));
        a0 += v0 * bf16_lo_f32(w0.x);
        a1 += v0 * bf16_hi_f32(w0.x);
        a2 += v0 * bf16_lo_f32(w0.y);
        a3 += v0 * bf16_hi_f32(w0.y);
        a4 += v0 * bf16_lo_f32(w0.z);
        a5 += v0 * bf16_hi_f32(w0.z);
        a6 += v0 * bf16_lo_f32(w0.w);
        a7 += v0 * bf16_hi_f32(w0.w);
    }
    // merge the 4 edge-groups (xor over lane bits 4,5)
    a0 += __shfl_xor(a0, 16); a0 += __shfl_xor(a0, 32);
    a1 += __shfl_xor(a1, 16); a1 += __shfl_xor(a1, 32);
    a2 += __shfl_xor(a2, 16); a2 += __shfl_xor(a2, 32);
    a3 += __shfl_xor(a3, 16); a3 += __shfl_xor(a3, 32);
    a4 += __shfl_xor(a4, 16); a4 += __shfl_xor(a4, 32);
    a5 += __shfl_xor(a5, 16); a5 += __shfl_xor(a5, 32);
    a6 += __shfl_xor(a6, 16); a6 += __shfl_xor(a6, 32);
    a7 += __shfl_xor(a7, 16); a7 += __shfl_xor(a7, 32);

    if (lane < 13) {
        float* zp = Z + (long long)r * OUTPUT_DIM + i * HIDDEN + lane * 8;
        float4 o0, o1;
        o0.x = a0 > 0.f ? a0 : 0.f;
        o0.y = a1 > 0.f ? a1 : 0.f;
        o0.z = a2 > 0.f ? a2 : 0.f;
        o0.w = a3 > 0.f ? a3 : 0.f;
        *(float4*)zp = o0;                       // cols 8*lane .. +3
        if (lane < 12) {
            o1.x = a4 > 0.f ? a4 : 0.f;
            o1.y = a5 > 0.f ? a5 : 0.f;
            o1.z = a6 > 0.f ? a6 : 0.f;
            o1.w = a7 > 0.f ? a7 : 0.f;
            *(float4*)(zp + 4) = o1;             // cols 8*lane+4 .. +7
        }
    }
}

// ---------------------------------------------------------------------------
// Fallback path: f32 GEMM + COO atomic scatter (only if ws too small)
// ---------------------------------------------------------------------------
#define TM 64
#define TN 64
#define TK 16

__global__ __launch_bounds__(256) void gemm_f32(
    const float* __restrict__ A, const float* __restrict__ B,
    float* __restrict__ C, int M, int N, int K, int ldc)
{
    __shared__ float Asl[TK][TM + 4];
    __shared__ float Bsl[TK][TN + 4];
    const int tid = threadIdx.x;
    const int tx  = tid & 15;
    const int ty  = tid >> 4;
    const int row0 = blockIdx.x * TM;
    const int col0 = blockIdx.y * TN;
    float acc[4][4] = {};
    for (int k0 = 0; k0 < K; k0 += TK) {
        #pragma unroll
        for (int it = 0; it < (TM * TK) / 256; ++it) {
            int idx = tid + it * 256;
            int m = idx >> 4, kk = idx & 15, gr = row0 + m;
            Asl[kk][m] = (gr < M) ? A[(long long)gr * K + (k0 + kk)] : 0.f;
        }
        #pragma unroll
        for (int it = 0; it < (TK * TN) / 256; ++it) {
            int idx = tid + it * 256;
            int kk = idx >> 6, n = idx & 63, gc = col0 + n;
            Bsl[kk][n] = (gc < N) ? B[(long long)(k0 + kk) * N + gc] : 0.f;
        }
        __syncthreads();
        #pragma unroll
        for (int kk = 0; kk < TK; ++kk) {
            float a[4], b[4];
            #pragma unroll
            for (int u = 0; u < 4; ++u) a[u] = Asl[kk][ty * 4 + u];
            #pragma unroll
            for (int v = 0; v < 4; ++v) b[v] = Bsl[kk][tx * 4 + v];
            #pragma unroll
            for (int u = 0; u < 4; ++u)
                #pragma unroll
                for (int v = 0; v < 4; ++v)
                    acc[u][v] += a[u] * b[v];
        }
        __syncthreads();
    }
    #pragma unroll
    for (int u = 0; u < 4; ++u) {
        int gr = row0 + ty * 4 + u;
        if (gr >= M) continue;
        #pragma unroll
        for (int v = 0; v < 4; ++v) {
            int gc = col0 + tx * 4 + v;
            if (gc < N) C[(long long)gr * ldc + gc] = acc[u][v];
        }
    }
}

__global__ __launch_bounds__(256) void scatter_edges(
    const float* __restrict__ sup_vals,
    const int*   __restrict__ sup_rows,
    const int*   __restrict__ sup_cols,
    const float* __restrict__ XU, const float* __restrict__ XV,
    float* __restrict__ z_u, float* __restrict__ z_v)
{
    const unsigned t = blockIdx.x * 256u + threadIdx.x;
    const unsigned total = (unsigned)NEDGE * HIDDEN;
    if (t >= total) return;
    const unsigned j  = t % HIDDEN;
    const unsigned eg = t / HIDDEN;
    const unsigned i  = eg / NNZ;
    const float val = sup_vals[eg];
    const int   r   = sup_rows[eg];
    const int   c   = sup_cols[eg];
    const int   colOff = i * HIDDEN + j;
    atomicAdd(&z_u[(long long)r * OUTPUT_DIM + colOff],
              val * XV[(long long)c * NPAD + colOff]);
    atomicAdd(&z_v[(long long)c * OUTPUT_DIM + colOff],
              val * XU[(long long)r * NPAD + colOff]);
}

__global__ __launch_bounds__(256) void relu_inplace(float4* __restrict__ p, int n4)
{
    int t = blockIdx.x * 256 + threadIdx.x;
    if (t >= n4) return;
    float4 v = p[t];
    v.x = v.x > 0.f ? v.x : 0.f;
    v.y = v.y > 0.f ? v.y : 0.f;
    v.z = v.z > 0.f ? v.z : 0.f;
    v.w = v.w > 0.f ? v.w : 0.f;
    p[t] = v;
}

extern "C" void kernel_launch(void* const* d_in, const int* in_sizes, int n_in,
                              void* d_out, int out_size, void* d_ws, size_t ws_size,
                              hipStream_t stream)
{
    const float* x_u      = (const float*)d_in[0];
    const float* x_v      = (const float*)d_in[1];
    const float* W        = (const float*)d_in[2];
    const float* sup_vals = (const float*)d_in[3];
    const int*   sup_rows = (const int*)d_in[4];
    const int*   sup_cols = (const int*)d_in[5];

    float* z_u = (float*)d_out;
    float* z_v = z_u + (long long)NUM_USERS * OUTPUT_DIM;

    const long long NU = (long long)NUM_USERS * 512;   // bf16 input elems (25.6M)
    const long long NV = (long long)NUM_ITEMS * 512;   //  5.12M
    const long long PU = (long long)NUM_SUPPORT * NUM_USERS * HPAD;  // 32M
    const long long PV = (long long)NUM_SUPPORT * NUM_ITEMS * HPAD;  // 6.4M
    const int NRU = NUM_SUPPORT * NUM_USERS;  // 250000 keys (u side)
    const int NRV = NUM_SUPPORT * NUM_ITEMS;  //  50000 keys (v side)

    // ---- full-path workspace layout (139.97 MB) ----
    ushort_t* Xp_u  = (ushort_t*)d_ws;        // packed gemm out [5][50000][128]
    ushort_t* Xp_v  = Xp_u + PU;              // packed gemm out [5][10000][128]
    ushort_t* xu_in = Xp_v + PV;              // bf16(x_u); reused as scratch post-GEMM
    ushort_t* xv_in = xu_in + NU;             // bf16(x_v)
    ushort_t* WbT   = xv_in + NV;             // bf16 W^T padded [512][512]
    u32* row_ptr_u  = (u32*)(WbT + 512 * 512);     // [NRU+1]
    u32* col_ptr_v  = row_ptr_u + (NRU + 1);       // [NRV+1]
    u32* partials   = col_ptr_v + (NRV + 1);       // [1024]
    size_t need_full = ((char*)(partials + 1024)) - ((char*)d_ws);

    // scratch aliases inside xu_in (only used AFTER both GEMMs consumed it):
    // buf(16MB) + histm(0.96MB) + perm_u(16MB) + perm_v(16MB) = 48.96MB <= 51.2MB
    uint2* buf    = (uint2*)xu_in;            // [NEDGE] phase-B staging
    u32*   histm  = (u32*)(buf + NEDGE);      // [HISTM_MAX] bucket x chunk matrix
    uint2* perm_u = (uint2*)(histm + HISTM_MAX);   // [NEDGE] final (val,gidx)
    uint2* perm_v = perm_u + NEDGE;                // [NEDGE]

    dim3 blk(256);

    if (ws_size >= need_full) {
        // ---- dense projections (bf16 MFMA, packed epilogue) ----
        cvt_bf16<<<(int)((NU / 4 + 255) / 256), blk, 0, stream>>>(
            (const float4*)x_u, (ushort4*)xu_in, (int)(NU / 4));
        cvt_bf16<<<(int)((NV / 4 + 255) / 256), blk, 0, stream>>>(
            (const float4*)x_v, (ushort4*)xv_in, (int)(NV / 4));
        make_WbT<<<(512 * 512) / 256, blk, 0, stream>>>(W, WbT);
        gemm_mfma_bf16<<<dim3((NUM_USERS + BM - 1) / BM, 512 / BN), blk, 0, stream>>>(
            xu_in, WbT, Xp_u, NUM_USERS);
        gemm_mfma_bf16<<<dim3((NUM_ITEMS + BM - 1) / BM, 512 / BN), blk, 0, stream>>>(
            xv_in, WbT, Xp_v, NUM_ITEMS);

        // xu_in is now dead -> buf/histm/perm_u/perm_v scratch is live.
        auto scan_u32 = [&](u32* data, int n) {
            int nb = (n + 1023) / 1024;
            scan1<<<nb, blk, 0, stream>>>(data, n, partials);
            scan_partials<<<1, blk, 0, stream>>>(partials, nb);
            scan_add<<<(n + 255) / 256, blk, 0, stream>>>(data, n, partials);
        };

        // ---- u-side partition: key = i*NUM_USERS + row, gidx = col (14 bits) ----
        chunk_hist<NUM_USERS><<<NCHUNK, blk, 0, stream>>>(sup_rows, histm);
        scan_u32(histm, NB_U * NCHUNK);                       // 239365 <= 262144
        partition_edges<NUM_USERS, 14><<<NCHUNK, blk, 0, stream>>>(
            sup_rows, sup_cols, sup_vals, histm, buf);
        bucket_scatter<NUM_USERS, 14><<<NB_U, blk, 0, stream>>>(
            buf, histm, row_ptr_u, perm_u);

        // ---- v-side partition: key = i*NUM_ITEMS + col, gidx = row (16 bits) ----
        chunk_hist<NUM_ITEMS><<<NCHUNK, blk, 0, stream>>>(sup_cols, histm);
        scan_u32(histm, NB_V * NCHUNK);                       // 48020
        partition_edges<NUM_ITEMS, 16><<<NCHUNK, blk, 0, stream>>>(
            sup_cols, sup_rows, sup_vals, histm, buf);
        bucket_scatter<NUM_ITEMS, 16><<<NB_V, blk, 0, stream>>>(
            buf, histm, col_ptr_v, perm_v);

        set_sentinels<<<1, 1, 0, stream>>>(row_ptr_u + NRU, col_ptr_v + NRV);

        // ---- SpMM (fused ReLU) ----
        spmm_pack<NUM_USERS><<<(NRU * 64 + 255) / 256, blk, 0, stream>>>(
            row_ptr_u, perm_u, Xp_v, z_u, NUM_ITEMS);
        spmm_pack<NUM_ITEMS><<<(NRV * 64 + 255) / 256, blk, 0, stream>>>(
            col_ptr_v, perm_v, Xp_u, z_v, NUM_USERS);
    } else {
        // ---- fallback: f32 GEMM + atomic scatter ----
        float* XU = (float*)d_ws;
        float* XV = XU + (long long)NUM_USERS * NPAD;
        gemm_f32<<<dim3((NUM_USERS + TM - 1) / TM, (OUTPUT_DIM + TN - 1) / TN),
                   blk, 0, stream>>>(x_u, W, XU, NUM_USERS, OUTPUT_DIM, INPUT_DIM, NPAD);
        gemm_f32<<<dim3((NUM_ITEMS + TM - 1) / TM, (OUTPUT_DIM + TN - 1) / TN),
                   blk, 0, stream>>>(x_v, W, XV, NUM_ITEMS, OUTPUT_DIM, INPUT_DIM, NPAD);
        hipMemsetAsync(d_out, 0, (size_t)out_size * sizeof(float), stream);
        unsigned total = (unsigned)NEDGE * HIDDEN;
        scatter_edges<<<(total + 255u) / 256u, blk, 0, stream>>>(
            sup_vals, sup_rows, sup_cols, XU, XV, z_u, z_v);
        int n4 = out_size / 4;
        relu_inplace<<<(n4 + 255) / 256, blk, 0, stream>>>((float4*)d_out, n4);
    }
}

// Round 4
// 568.292 us; speedup vs baseline: 2.1149x; 1.0226x over previous
//
#include <hip/hip_runtime.h>

// Problem constants (match reference)
#define NUM_USERS   50000
#define NUM_ITEMS   10000
#define NUM_SUPPORT 5
#define INPUT_DIM   512      // K
#define OUTPUT_DIM  500
#define NPAD        512      // padded output-dim stride (fallback path only)
#define HIDDEN      100      // OUTPUT_DIM / NUM_SUPPORT
#define HPAD        128      // packed per-support row: 100 bf16 padded to 128 (256B)
#define NNZ         400000
#define NEDGE       (NUM_SUPPORT * NNZ)     // 2,000,000

// radix-partition parameters
#define CH_E        8192                         // edges per chunk
#define NCHUNK      ((NEDGE + CH_E - 1) / CH_E)  // 245
#define NB_U        ((NUM_SUPPORT * NUM_USERS + 255) / 256)   // 977
#define NB_V        ((NUM_SUPPORT * NUM_ITEMS + 255) / 256)   // 196
#define HISTM_U_SZ  (NB_U * NCHUNK)              // 239365
#define HISTM_U_PAD 239366                       // 8B-align the next region
#define HISTM_V_SZ  (NB_V * NCHUNK)              // 48020

typedef unsigned int u32;
typedef unsigned short ushort_t;
typedef __attribute__((ext_vector_type(4))) float f32x4;
typedef __attribute__((ext_vector_type(8))) short bf16x8;   // 8 bf16 in 4 VGPRs

// async global->LDS, 16B per lane. LDS side must be wave-uniform base + lane*16.
#define GLDS(g, l) __builtin_amdgcn_global_load_lds( \
    (const __attribute__((address_space(1))) unsigned int*)(g), \
    (__attribute__((address_space(3))) unsigned int*)(l), 16, 0, 0)

__device__ inline ushort_t bf16_rne(float f) {
    u32 u = __float_as_uint(f);
    u32 r = (u + 0x7FFFu + ((u >> 16) & 1u)) >> 16;
    return (ushort_t)r;
}
__device__ inline float bf16_lo_f32(u32 w) { return __uint_as_float(w << 16); }
__device__ inline float bf16_hi_f32(u32 w) { return __uint_as_float(w & 0xFFFF0000u); }

// ---------------------------------------------------------------------------
// f32 -> bf16 conversion, 4 elems/thread
// ---------------------------------------------------------------------------
__global__ __launch_bounds__(256) void cvt_bf16(
    const float4* __restrict__ in, ushort4* __restrict__ out, int n4)
{
    int t = blockIdx.x * 256 + threadIdx.x;
    if (t >= n4) return;
    float4 v = in[t];
    ushort4 o;
    o.x = bf16_rne(v.x); o.y = bf16_rne(v.y);
    o.z = bf16_rne(v.z); o.w = bf16_rne(v.w);
    out[t] = o;
}

// WbT[n][k] = W[k][n] (bf16), n padded 500->512 with zeros. 512x512.
__global__ __launch_bounds__(256) void make_WbT(
    const float* __restrict__ W, ushort_t* __restrict__ WbT)
{
    int t = blockIdx.x * 256 + threadIdx.x;
    int n = t >> 9, k = t & 511;
    float v = (n < OUTPUT_DIM) ? W[k * OUTPUT_DIM + n] : 0.f;
    WbT[t] = bf16_rne(v);
}

// ---------------------------------------------------------------------------
// MFMA bf16 GEMM: Xp[seg][M][128](bf16) = packed A @ BT^T
// 128x128 tile, BK=32, 256 thr (4 waves, each 64x64 = 4x4 tiles of 16x16x32).
// Epilogue writes support-major packed layout: col c -> seg=c/100, off=c%100.
// ---------------------------------------------------------------------------
#define BM 128
#define BN 128
#define BK 32

__global__ __launch_bounds__(256) void gemm_mfma_bf16(
    const ushort_t* __restrict__ A,    // [M][512] bf16
    const ushort_t* __restrict__ BT,   // [512][512] bf16 (BT[n][k])
    ushort_t* __restrict__ Xp,         // [5][M][HPAD] bf16 packed
    int M)
{
    const int K = INPUT_DIM;
    __shared__ ushort_t As[BM * BK];   // [m][k], 64B rows
    __shared__ ushort_t Bs[BN * BK];   // [n][k], 64B rows

    const int tid  = threadIdx.x;
    const int wave = tid >> 6;
    const int lane = tid & 63;
    const int quad = lane >> 4;
    const int lr   = lane & 15;
    const int m0 = blockIdx.x * BM;
    const int n0 = blockIdx.y * BN;
    const int wm = (wave >> 1) * 64;
    const int wn = (wave & 1) * 64;

    f32x4 acc[4][4] = {};

    for (int k0 = 0; k0 < K; k0 += BK) {
        #pragma unroll
        for (int h = 0; h < 2; ++h) {
            int o   = tid * 16 + h * 4096;
            int row = o >> 6;
            int byt = o & 63;
            int gr  = m0 + row; if (gr >= M) gr = M - 1;   // clamp (masked at store)
            GLDS((const char*)A + ((long long)gr * K + k0) * 2 + byt, (char*)As + o);
        }
        #pragma unroll
        for (int h = 0; h < 2; ++h) {
            int o   = tid * 16 + h * 4096;
            int row = o >> 6;
            int byt = o & 63;
            GLDS((const char*)BT + ((long long)(n0 + row) * K + k0) * 2 + byt, (char*)Bs + o);
        }
        asm volatile("s_waitcnt vmcnt(0)" ::: "memory");
        __syncthreads();

        bf16x8 af[4], bfr[4];
        #pragma unroll
        for (int tm = 0; tm < 4; ++tm)
            af[tm] = *(const bf16x8*)(As + (wm + tm * 16 + lr) * BK + quad * 8);
        #pragma unroll
        for (int tn = 0; tn < 4; ++tn)
            bfr[tn] = *(const bf16x8*)(Bs + (wn + tn * 16 + lr) * BK + quad * 8);
        #pragma unroll
        for (int tm = 0; tm < 4; ++tm)
            #pragma unroll
            for (int tn = 0; tn < 4; ++tn)
                acc[tm][tn] = __builtin_amdgcn_mfma_f32_16x16x32_bf16(
                    af[tm], bfr[tn], acc[tm][tn], 0, 0, 0);
        __syncthreads();
    }

    // epilogue: C/D layout col=lane&15, row=quad*4+reg; scatter into packed Xp
    #pragma unroll
    for (int tm = 0; tm < 4; ++tm) {
        int rbase = m0 + wm + tm * 16 + quad * 4;
        #pragma unroll
        for (int tn = 0; tn < 4; ++tn) {
            int col = n0 + wn + tn * 16 + lr;
            if (col >= OUTPUT_DIM) continue;
            int seg = col / HIDDEN;             // const-div -> magic mul
            int off = col - seg * HIDDEN;
            ushort_t* dst = Xp + (long long)seg * M * HPAD + off;
            #pragma unroll
            for (int g = 0; g < 4; ++g) {
                int row = rbase + g;
                if (row < M) dst[(long long)row * HPAD] = bf16_rne(acc[tm][tn][g]);
            }
        }
    }
}

// ---------------------------------------------------------------------------
// Scan helpers (exclusive scan over u32 arrays, n <= 262144)
// ---------------------------------------------------------------------------
__global__ __launch_bounds__(256) void scan1(u32* __restrict__ data, int n,
                                             u32* __restrict__ partials)
{
    __shared__ u32 sh[256];
    int t = threadIdx.x;
    int base = blockIdx.x * 1024 + t * 4;
    u32 x[4];
    #pragma unroll
    for (int k = 0; k < 4; ++k) {
        int idx = base + k;
        x[k] = (idx < n) ? data[idx] : 0u;
    }
    u32 tsum = x[0] + x[1] + x[2] + x[3];
    sh[t] = tsum;
    __syncthreads();
    for (int off = 1; off < 256; off <<= 1) {
        u32 v = (t >= off) ? sh[t - off] : 0u;
        __syncthreads();
        sh[t] += v;
        __syncthreads();
    }
    u32 run = (t > 0) ? sh[t - 1] : 0u;
    if (t == 255) partials[blockIdx.x] = sh[255];
    #pragma unroll
    for (int k = 0; k < 4; ++k) {
        int idx = base + k;
        if (idx < n) data[idx] = run;
        run += x[k];
    }
}

__global__ __launch_bounds__(256) void scan_partials(u32* __restrict__ partials, int n)
{
    __shared__ u32 sh[256];
    int t = threadIdx.x;
    u32 x = (t < n) ? partials[t] : 0u;
    sh[t] = x;
    __syncthreads();
    for (int off = 1; off < 256; off <<= 1) {
        u32 v = (t >= off) ? sh[t - off] : 0u;
        __syncthreads();
        sh[t] += v;
        __syncthreads();
    }
    if (t < n) partials[t] = (t > 0) ? sh[t - 1] : 0u;
}

__global__ __launch_bounds__(256) void scan_add(u32* __restrict__ data, int n,
                                                const u32* __restrict__ partials)
{
    int idx = blockIdx.x * 256 + threadIdx.x;
    if (idx < n) data[idx] += partials[idx >> 10];
}

// ---------------------------------------------------------------------------
// Chunked radix partition (no global atomics, no line-amplified scatter).
// Fused histogram: one pass reads rows+cols, builds both bucket matrices.
// ---------------------------------------------------------------------------
__global__ __launch_bounds__(256) void hist_uv(
    const int* __restrict__ rows, const int* __restrict__ cols,
    u32* __restrict__ histm_u, u32* __restrict__ histm_v)
{
    __shared__ u32 hu[NB_U];
    __shared__ u32 hv[NB_V];
    const int tid = threadIdx.x;
    const int c = blockIdx.x;
    for (int b = tid; b < NB_U; b += 256) hu[b] = 0u;
    for (int b = tid; b < NB_V; b += 256) hv[b] = 0u;
    __syncthreads();
    int base = c * CH_E;
    int end = base + CH_E; if (end > NEDGE) end = NEDGE;
    for (int e = base + tid; e < end; e += 256) {
        unsigned i = (unsigned)e / (unsigned)NNZ;
        u32 ku = i * (u32)NUM_USERS + (u32)rows[e];
        u32 kv = i * (u32)NUM_ITEMS + (u32)cols[e];
        atomicAdd(&hu[ku >> 8], 1u);
        atomicAdd(&hv[kv >> 8], 1u);
    }
    __syncthreads();
    for (int b = tid; b < NB_U; b += 256) histm_u[b * NCHUNK + c] = hu[b];
    for (int b = tid; b < NB_V; b += 256) histm_v[b * NCHUNK + c] = hv[b];
}

template<int NROWS, int GSHIFT>
__global__ __launch_bounds__(256) void partition_edges(
    const int* __restrict__ keyidx, const int* __restrict__ gidx,
    const float* __restrict__ vals,
    const u32* __restrict__ histm, uint2* __restrict__ buf)
{
    constexpr int NKEY = NUM_SUPPORT * NROWS;
    constexpr int NB = (NKEY + 255) / 256;
    __shared__ u32 cur[NB];
    const int tid = threadIdx.x;
    const int c = blockIdx.x;
    for (int b = tid; b < NB; b += 256) cur[b] = histm[b * NCHUNK + c];
    __syncthreads();
    int base = c * CH_E;
    int end = base + CH_E; if (end > NEDGE) end = NEDGE;
    for (int e = base + tid; e < end; e += 256) {
        unsigned i = (unsigned)e / (unsigned)NNZ;
        u32 key = i * (u32)NROWS + (u32)keyidx[e];
        u32 p = atomicAdd(&cur[key >> 8], 1u);
        uint2 pay;
        pay.x = __float_as_uint(vals[e]);
        pay.y = (key << GSHIFT) | (u32)gidx[e];
        buf[p] = pay;
    }
}

template<int NROWS, int GSHIFT>
__global__ __launch_bounds__(256) void bucket_scatter(
    const uint2* __restrict__ buf, const u32* __restrict__ histm,
    u32* __restrict__ ptr, uint2* __restrict__ perm)
{
    constexpr int NKEY = NUM_SUPPORT * NROWS;
    constexpr int NB = (NKEY + 255) / 256;
    __shared__ u32 cnt[256];
    __shared__ u32 scn[256];
    const int tid = threadIdx.x;
    const int b = blockIdx.x;
    const u32 key0 = (u32)b << 8;
    const u32 start = histm[b * NCHUNK];
    const u32 bend  = (b + 1 < NB) ? histm[(b + 1) * NCHUNK] : (u32)NEDGE;
    if (b == 0 && tid == 0) ptr[NKEY] = (u32)NEDGE;   // CSR sentinel (fused)
    cnt[tid] = 0u;
    __syncthreads();
    for (u32 j = start + tid; j < bend; j += 256) {
        u32 key = buf[j].y >> GSHIFT;
        atomicAdd(&cnt[key - key0], 1u);
    }
    __syncthreads();
    scn[tid] = cnt[tid];
    __syncthreads();
    for (int off = 1; off < 256; off <<= 1) {
        u32 v = (tid >= off) ? scn[tid - off] : 0u;
        __syncthreads();
        scn[tid] += v;
        __syncthreads();
    }
    u32 myoff = start + scn[tid] - cnt[tid];   // exclusive within bucket
    if (key0 + (u32)tid < (u32)NKEY) ptr[key0 + tid] = myoff;
    __syncthreads();
    cnt[tid] = myoff;                          // becomes running cursor
    __syncthreads();
    for (u32 j = start + tid; j < bend; j += 256) {
        uint2 q = buf[j];
        u32 key = q.y >> GSHIFT;
        u32 p = atomicAdd(&cnt[key - key0], 1u);
        uint2 out;
        out.x = q.x;
        out.y = q.y & ((1u << GSHIFT) - 1u);
        perm[p] = out;
    }
}

// ---------------------------------------------------------------------------
// Packed SpMM, 4 rows per wave: each 16-lane group owns one CSR key (row),
// iterates its own edges (predicated unroll-2 -> 8 gathers in flight/wave).
// Each lane gathers 16B (8 bf16 cols) of the 256B packed row -> lanes hold
// the final accumulators directly: NO cross-group shuffle merge.
// Fused ReLU; per group, lanes 0..12 write the 100 f32.
// ---------------------------------------------------------------------------
template<int NROWS>
__global__ __launch_bounds__(256) void spmm_pack4(
    const u32* __restrict__ ptr,      // [5*NROWS + 1] CSR offsets
    const uint2* __restrict__ perm,   // [NEDGE] (val_bits, gather_idx)
    const ushort_t* __restrict__ Xp,  // [5][nsrc][HPAD] bf16 packed
    float* __restrict__ Z,            // [NROWS][OUTPUT_DIM] f32
    int nsrc)
{
    constexpr int NKEY = NUM_SUPPORT * NROWS;
    int w = (int)((blockIdx.x * 256u + threadIdx.x) >> 6);
    w = __builtin_amdgcn_readfirstlane(w);
    if (w * 4 >= NKEY) return;
    const int lane = threadIdx.x & 63;
    const int g  = lane >> 4;     // group 0..3 -> row w*4+g
    const int sl = lane & 15;     // 8 bf16 cols per lane

    int key = w * 4 + g;
    bool live = key < NKEY;
    int kc = live ? key : (NKEY - 1);
    int i = kc / NROWS;           // support segment
    int r = kc - i * NROWS;       // output row
    u32 s = ptr[kc];
    u32 e = live ? ptr[kc + 1] : s;

    const ushort_t* Xs = Xp + (long long)i * nsrc * HPAD + sl * 8;

    // wave-max trip count (groups differ only in lane bits 4..5)
    u32 cnt = e - s;
    u32 m = cnt;
    { u32 t = (u32)__shfl_xor((int)m, 16); m = m > t ? m : t; }
    { u32 t = (u32)__shfl_xor((int)m, 32); m = m > t ? m : t; }
    int iters = (int)((m + 1) >> 1);

    float a0 = 0.f, a1 = 0.f, a2 = 0.f, a3 = 0.f;
    float a4 = 0.f, a5 = 0.f, a6 = 0.f, a7 = 0.f;
    u32 k = s;
    for (int it = 0; it < iters; ++it) {
        bool p0 = k < e, p1 = (k + 1) < e;
        u32 j0 = p0 ? k : 0u;
        u32 j1 = p1 ? (k + 1) : 0u;
        uint2 q0 = perm[j0], q1 = perm[j1];
        float v0 = p0 ? __uint_as_float(q0.x) : 0.f;
        float v1 = p1 ? __uint_as_float(q1.x) : 0.f;
        uint4 w0 = *(const uint4*)(Xs + ((long long)q0.y << 7));
        uint4 w1 = *(const uint4*)(Xs + ((long long)q1.y << 7));
        a0 += v0 * bf16_lo_f32(w0.x) + v1 * bf16_lo_f32(w1.x);
        a1 += v0 * bf16_hi_f32(w0.x) + v1 * bf16_hi_f32(w1.x);
        a2 += v0 * bf16_lo_f32(w0.y) + v1 * bf16_lo_f32(w1.y);
        a3 += v0 * bf16_hi_f32(w0.y) + v1 * bf16_hi_f32(w1.y);
        a4 += v0 * bf16_lo_f32(w0.z) + v1 * bf16_lo_f32(w1.z);
        a5 += v0 * bf16_hi_f32(w0.z) + v1 * bf16_hi_f32(w1.z);
        a6 += v0 * bf16_lo_f32(w0.w) + v1 * bf16_lo_f32(w1.w);
        a7 += v0 * bf16_hi_f32(w0.w) + v1 * bf16_hi_f32(w1.w);
        k += 2;
    }

    if (live && sl < 13) {
        float* zp = Z + (long long)r * OUTPUT_DIM + i * HIDDEN + sl * 8;
        float4 o0;
        o0.x = a0 > 0.f ? a0 : 0.f;
        o0.y = a1 > 0.f ? a1 : 0.f;
        o0.z = a2 > 0.f ? a2 : 0.f;
        o0.w = a3 > 0.f ? a3 : 0.f;
        *(float4*)zp = o0;                       // cols 8*sl .. +3
        if (sl < 12) {
            float4 o1;
            o1.x = a4 > 0.f ? a4 : 0.f;
            o1.y = a5 > 0.f ? a5 : 0.f;
            o1.z = a6 > 0.f ? a6 : 0.f;
            o1.w = a7 > 0.f ? a7 : 0.f;
            *(float4*)(zp + 4) = o1;             // cols 8*sl+4 .. +7
        }
    }
}

// ---------------------------------------------------------------------------
// Fallback path: f32 GEMM + COO atomic scatter (only if ws too small)
// ---------------------------------------------------------------------------
#define TM 64
#define TN 64
#define TK 16

__global__ __launch_bounds__(256) void gemm_f32(
    const float* __restrict__ A, const float* __restrict__ B,
    float* __restrict__ C, int M, int N, int K, int ldc)
{
    __shared__ float Asl[TK][TM + 4];
    __shared__ float Bsl[TK][TN + 4];
    const int tid = threadIdx.x;
    const int tx  = tid & 15;
    const int ty  = tid >> 4;
    const int row0 = blockIdx.x * TM;
    const int col0 = blockIdx.y * TN;
    float acc[4][4] = {};
    for (int k0 = 0; k0 < K; k0 += TK) {
        #pragma unroll
        for (int it = 0; it < (TM * TK) / 256; ++it) {
            int idx = tid + it * 256;
            int m = idx >> 4, kk = idx & 15, gr = row0 + m;
            Asl[kk][m] = (gr < M) ? A[(long long)gr * K + (k0 + kk)] : 0.f;
        }
        #pragma unroll
        for (int it = 0; it < (TK * TN) / 256; ++it) {
            int idx = tid + it * 256;
            int kk = idx >> 6, n = idx & 63, gc = col0 + n;
            Bsl[kk][n] = (gc < N) ? B[(long long)(k0 + kk) * N + gc] : 0.f;
        }
        __syncthreads();
        #pragma unroll
        for (int kk = 0; kk < TK; ++kk) {
            float a[4], b[4];
            #pragma unroll
            for (int u = 0; u < 4; ++u) a[u] = Asl[kk][ty * 4 + u];
            #pragma unroll
            for (int v = 0; v < 4; ++v) b[v] = Bsl[kk][tx * 4 + v];
            #pragma unroll
            for (int u = 0; u < 4; ++u)
                #pragma unroll
                for (int v = 0; v < 4; ++v)
                    acc[u][v] += a[u] * b[v];
        }
        __syncthreads();
    }
    #pragma unroll
    for (int u = 0; u < 4; ++u) {
        int gr = row0 + ty * 4 + u;
        if (gr >= M) continue;
        #pragma unroll
        for (int v = 0; v < 4; ++v) {
            int gc = col0 + tx * 4 + v;
            if (gc < N) C[(long long)gr * ldc + gc] = acc[u][v];
        }
    }
}

__global__ __launch_bounds__(256) void scatter_edges(
    const float* __restrict__ sup_vals,
    const int*   __restrict__ sup_rows,
    const int*   __restrict__ sup_cols,
    const float* __restrict__ XU, const float* __restrict__ XV,
    float* __restrict__ z_u, float* __restrict__ z_v)
{
    const unsigned t = blockIdx.x * 256u + threadIdx.x;
    const unsigned total = (unsigned)NEDGE * HIDDEN;
    if (t >= total) return;
    const unsigned j  = t % HIDDEN;
    const unsigned eg = t / HIDDEN;
    const unsigned i  = eg / NNZ;
    const float val = sup_vals[eg];
    const int   r   = sup_rows[eg];
    const int   c   = sup_cols[eg];
    const int   colOff = i * HIDDEN + j;
    atomicAdd(&z_u[(long long)r * OUTPUT_DIM + colOff],
              val * XV[(long long)c * NPAD + colOff]);
    atomicAdd(&z_v[(long long)c * OUTPUT_DIM + colOff],
              val * XU[(long long)r * NPAD + colOff]);
}

__global__ __launch_bounds__(256) void relu_inplace(float4* __restrict__ p, int n4)
{
    int t = blockIdx.x * 256 + threadIdx.x;
    if (t >= n4) return;
    float4 v = p[t];
    v.x = v.x > 0.f ? v.x : 0.f;
    v.y = v.y > 0.f ? v.y : 0.f;
    v.z = v.z > 0.f ? v.z : 0.f;
    v.w = v.w > 0.f ? v.w : 0.f;
    p[t] = v;
}

extern "C" void kernel_launch(void* const* d_in, const int* in_sizes, int n_in,
                              void* d_out, int out_size, void* d_ws, size_t ws_size,
                              hipStream_t stream)
{
    const float* x_u      = (const float*)d_in[0];
    const float* x_v      = (const float*)d_in[1];
    const float* W        = (const float*)d_in[2];
    const float* sup_vals = (const float*)d_in[3];
    const int*   sup_rows = (const int*)d_in[4];
    const int*   sup_cols = (const int*)d_in[5];

    float* z_u = (float*)d_out;
    float* z_v = z_u + (long long)NUM_USERS * OUTPUT_DIM;

    const long long NU = (long long)NUM_USERS * 512;   // bf16 input elems (25.6M)
    const long long NV = (long long)NUM_ITEMS * 512;   //  5.12M
    const long long PU = (long long)NUM_SUPPORT * NUM_USERS * HPAD;  // 32M
    const long long PV = (long long)NUM_SUPPORT * NUM_ITEMS * HPAD;  // 6.4M
    const int NRU = NUM_SUPPORT * NUM_USERS;  // 250000 keys (u side)
    const int NRV = NUM_SUPPORT * NUM_ITEMS;  //  50000 keys (v side)

    // ---- full-path workspace layout (~140 MB) ----
    ushort_t* Xp_u  = (ushort_t*)d_ws;        // packed gemm out [5][50000][128]
    ushort_t* Xp_v  = Xp_u + PU;              // packed gemm out [5][10000][128]
    ushort_t* xu_in = Xp_v + PV;              // bf16(x_u); reused as scratch post-GEMM
    ushort_t* xv_in = xu_in + NU;             // bf16(x_v)
    ushort_t* WbT   = xv_in + NV;             // bf16 W^T padded [512][512]
    u32* row_ptr_u  = (u32*)(WbT + 512 * 512);     // [NRU+1]
    u32* col_ptr_v  = row_ptr_u + (NRU + 1);       // [NRV+1]
    u32* partials   = col_ptr_v + (NRV + 1);       // [1024]
    size_t need_full = ((char*)(partials + 1024)) - ((char*)d_ws);

    // scratch aliases inside xu_in (only used AFTER both GEMMs consumed it):
    // buf 16MB + histm_u 0.96MB + histm_v 0.19MB + perm_u 16MB + perm_v 16MB
    //   = 49.15MB <= 51.2MB
    uint2* buf      = (uint2*)xu_in;               // [NEDGE] phase-B staging
    u32*   histm_u  = (u32*)(buf + NEDGE);         // [HISTM_U_PAD]
    u32*   histm_v  = histm_u + HISTM_U_PAD;       // [HISTM_V_SZ]
    uint2* perm_u   = (uint2*)(histm_v + HISTM_V_SZ);   // [NEDGE] (val,gidx)
    uint2* perm_v   = perm_u + NEDGE;                   // [NEDGE]

    dim3 blk(256);

    if (ws_size >= need_full) {
        // ---- dense projections (bf16 MFMA, packed epilogue) ----
        cvt_bf16<<<(int)((NU / 4 + 255) / 256), blk, 0, stream>>>(
            (const float4*)x_u, (ushort4*)xu_in, (int)(NU / 4));
        cvt_bf16<<<(int)((NV / 4 + 255) / 256), blk, 0, stream>>>(
            (const float4*)x_v, (ushort4*)xv_in, (int)(NV / 4));
        make_WbT<<<(512 * 512) / 256, blk, 0, stream>>>(W, WbT);
        gemm_mfma_bf16<<<dim3((NUM_USERS + BM - 1) / BM, 512 / BN), blk, 0, stream>>>(
            xu_in, WbT, Xp_u, NUM_USERS);
        gemm_mfma_bf16<<<dim3((NUM_ITEMS + BM - 1) / BM, 512 / BN), blk, 0, stream>>>(
            xv_in, WbT, Xp_v, NUM_ITEMS);

        // xu_in is now dead -> buf/histm/perm scratch is live.
        auto scan_u32 = [&](u32* data, int n) {
            int nb = (n + 1023) / 1024;
            scan1<<<nb, blk, 0, stream>>>(data, n, partials);
            scan_partials<<<1, blk, 0, stream>>>(partials, nb);
            scan_add<<<(n + 255) / 256, blk, 0, stream>>>(data, n, partials);
        };

        // ---- fused chunk histograms (reads rows+cols once) ----
        hist_uv<<<NCHUNK, blk, 0, stream>>>(sup_rows, sup_cols, histm_u, histm_v);

        // ---- u-side partition: key = i*NUM_USERS + row, gidx = col (14 bits) ----
        scan_u32(histm_u, HISTM_U_SZ);                        // 239365 <= 262144
        partition_edges<NUM_USERS, 14><<<NCHUNK, blk, 0, stream>>>(
            sup_rows, sup_cols, sup_vals, histm_u, buf);
        bucket_scatter<NUM_USERS, 14><<<NB_U, blk, 0, stream>>>(
            buf, histm_u, row_ptr_u, perm_u);

        // ---- v-side partition: key = i*NUM_ITEMS + col, gidx = row (16 bits) ----
        scan_u32(histm_v, HISTM_V_SZ);                        // 48020
        partition_edges<NUM_ITEMS, 16><<<NCHUNK, blk, 0, stream>>>(
            sup_cols, sup_rows, sup_vals, histm_v, buf);
        bucket_scatter<NUM_ITEMS, 16><<<NB_V, blk, 0, stream>>>(
            buf, histm_v, col_ptr_v, perm_v);

        // ---- SpMM (fused ReLU), 4 rows per wave ----
        spmm_pack4<NUM_USERS><<<((NRU / 4) * 64) / 256, blk, 0, stream>>>(
            row_ptr_u, perm_u, Xp_v, z_u, NUM_ITEMS);
        spmm_pack4<NUM_ITEMS><<<((NRV / 4) * 64) / 256, blk, 0, stream>>>(
            col_ptr_v, perm_v, Xp_u, z_v, NUM_USERS);
    } else {
        // ---- fallback: f32 GEMM + atomic scatter ----
        float* XU = (float*)d_ws;
        float* XV = XU + (long long)NUM_USERS * NPAD;
        gemm_f32<<<dim3((NUM_USERS + TM - 1) / TM, (OUTPUT_DIM + TN - 1) / TN),
                   blk, 0, stream>>>(x_u, W, XU, NUM_USERS, OUTPUT_DIM, INPUT_DIM, NPAD);
        gemm_f32<<<dim3((NUM_ITEMS + TM - 1) / TM, (OUTPUT_DIM + TN - 1) / TN),
                   blk, 0, stream>>>(x_v, W, XV, NUM_ITEMS, OUTPUT_DIM, INPUT_DIM, NPAD);
        hipMemsetAsync(d_out, 0, (size_t)out_size * sizeof(float), stream);
        unsigned total = (unsigned)NEDGE * HIDDEN;
        scatter_edges<<<(total + 255u) / 256u, blk, 0, stream>>>(
            sup_vals, sup_rows, sup_cols, XU, XV, z_u, z_v);
        int n4 = out_size / 4;
        relu_inplace<<<(n4 + 255) / 256, blk, 0, stream>>>((float4*)d_out, n4);
    }
}

// Round 5
// 519.245 us; speedup vs baseline: 2.3147x; 1.0945x over previous
//
#include <hip/hip_runtime.h>

// Problem constants (match reference)
#define NUM_USERS   50000
#define NUM_ITEMS   10000
#define NUM_SUPPORT 5
#define INPUT_DIM   512      // K
#define OUTPUT_DIM  500
#define NPAD        512      // padded output-dim stride (fallback path only)
#define HIDDEN      100      // OUTPUT_DIM / NUM_SUPPORT
#define HPAD        128      // packed per-support row: 100 bf16 padded to 128 (256B)
#define NNZ         400000
#define NEDGE       (NUM_SUPPORT * NNZ)     // 2,000,000

// radix-partition parameters
#define CH_E        8192                         // edges per chunk
#define NCHUNK      ((NEDGE + CH_E - 1) / CH_E)  // 245
#define NB_U        ((NUM_SUPPORT * NUM_USERS + 255) / 256)   // 977
#define NB_V        ((NUM_SUPPORT * NUM_ITEMS + 255) / 256)   // 196
#define HISTM_U_SZ  (NB_U * NCHUNK)              // 239365
#define HISTM_U_ALIGN 239616                     // 234*1024: pad so v region is block-aligned
#define HISTM_V_SZ  (NB_V * NCHUNK)              // 48020
#define HISTM_TOT   (HISTM_U_ALIGN + HISTM_V_SZ) // 287636 (combined scan length)

typedef unsigned int u32;
typedef unsigned short ushort_t;
typedef __attribute__((ext_vector_type(4))) float f32x4;
typedef __attribute__((ext_vector_type(8))) short bf16x8;   // 8 bf16 in 4 VGPRs

// async global->LDS, 16B per lane. LDS side must be wave-uniform base + lane*16.
#define GLDS(g, l) __builtin_amdgcn_global_load_lds( \
    (const __attribute__((address_space(1))) unsigned int*)(g), \
    (__attribute__((address_space(3))) unsigned int*)(l), 16, 0, 0)

__device__ inline ushort_t bf16_rne(float f) {
    u32 u = __float_as_uint(f);
    u32 r = (u + 0x7FFFu + ((u >> 16) & 1u)) >> 16;
    return (ushort_t)r;
}
__device__ inline float bf16_lo_f32(u32 w) { return __uint_as_float(w << 16); }
__device__ inline float bf16_hi_f32(u32 w) { return __uint_as_float(w & 0xFFFF0000u); }

// ---------------------------------------------------------------------------
// f32 -> bf16 conversion, both tensors in one launch
// ---------------------------------------------------------------------------
__global__ __launch_bounds__(256) void cvt_bf16_2(
    const float4* __restrict__ a, const float4* __restrict__ b,
    ushort4* __restrict__ oa, ushort4* __restrict__ ob, int na4, int nb4)
{
    int t = blockIdx.x * 256 + threadIdx.x;
    const float4* src;
    ushort4* dst;
    int idx;
    if (t < na4) { src = a; dst = oa; idx = t; }
    else { idx = t - na4; if (idx >= nb4) return; src = b; dst = ob; }
    float4 v = src[idx];
    ushort4 o;
    o.x = bf16_rne(v.x); o.y = bf16_rne(v.y);
    o.z = bf16_rne(v.z); o.w = bf16_rne(v.w);
    dst[idx] = o;
}

// WbT[n][k] = W[k][n] (bf16), n padded 500->512 with zeros. 512x512.
__global__ __launch_bounds__(256) void make_WbT(
    const float* __restrict__ W, ushort_t* __restrict__ WbT)
{
    int t = blockIdx.x * 256 + threadIdx.x;
    int n = t >> 9, k = t & 511;
    float v = (n < OUTPUT_DIM) ? W[k * OUTPUT_DIM + n] : 0.f;
    WbT[t] = bf16_rne(v);
}

// ---------------------------------------------------------------------------
// MFMA bf16 GEMM: Xp[seg][M][128](bf16) = packed A @ BT^T
// 128x128 tile, BK=32, 256 thr (4 waves, each 64x64 = 4x4 tiles of 16x16x32).
// Epilogue writes support-major packed layout: col c -> seg=c/100, off=c%100.
// ---------------------------------------------------------------------------
#define BM 128
#define BN 128
#define BK 32

__global__ __launch_bounds__(256) void gemm_mfma_bf16(
    const ushort_t* __restrict__ A,    // [M][512] bf16
    const ushort_t* __restrict__ BT,   // [512][512] bf16 (BT[n][k])
    ushort_t* __restrict__ Xp,         // [5][M][HPAD] bf16 packed
    int M)
{
    const int K = INPUT_DIM;
    __shared__ ushort_t As[BM * BK];   // [m][k], 64B rows
    __shared__ ushort_t Bs[BN * BK];   // [n][k], 64B rows

    const int tid  = threadIdx.x;
    const int wave = tid >> 6;
    const int lane = tid & 63;
    const int quad = lane >> 4;
    const int lr   = lane & 15;
    const int m0 = blockIdx.x * BM;
    const int n0 = blockIdx.y * BN;
    const int wm = (wave >> 1) * 64;
    const int wn = (wave & 1) * 64;

    f32x4 acc[4][4] = {};

    for (int k0 = 0; k0 < K; k0 += BK) {
        #pragma unroll
        for (int h = 0; h < 2; ++h) {
            int o   = tid * 16 + h * 4096;
            int row = o >> 6;
            int byt = o & 63;
            int gr  = m0 + row; if (gr >= M) gr = M - 1;   // clamp (masked at store)
            GLDS((const char*)A + ((long long)gr * K + k0) * 2 + byt, (char*)As + o);
        }
        #pragma unroll
        for (int h = 0; h < 2; ++h) {
            int o   = tid * 16 + h * 4096;
            int row = o >> 6;
            int byt = o & 63;
            GLDS((const char*)BT + ((long long)(n0 + row) * K + k0) * 2 + byt, (char*)Bs + o);
        }
        asm volatile("s_waitcnt vmcnt(0)" ::: "memory");
        __syncthreads();

        bf16x8 af[4], bfr[4];
        #pragma unroll
        for (int tm = 0; tm < 4; ++tm)
            af[tm] = *(const bf16x8*)(As + (wm + tm * 16 + lr) * BK + quad * 8);
        #pragma unroll
        for (int tn = 0; tn < 4; ++tn)
            bfr[tn] = *(const bf16x8*)(Bs + (wn + tn * 16 + lr) * BK + quad * 8);
        #pragma unroll
        for (int tm = 0; tm < 4; ++tm)
            #pragma unroll
            for (int tn = 0; tn < 4; ++tn)
                acc[tm][tn] = __builtin_amdgcn_mfma_f32_16x16x32_bf16(
                    af[tm], bfr[tn], acc[tm][tn], 0, 0, 0);
        __syncthreads();
    }

    // epilogue: C/D layout col=lane&15, row=quad*4+reg; scatter into packed Xp
    #pragma unroll
    for (int tm = 0; tm < 4; ++tm) {
        int rbase = m0 + wm + tm * 16 + quad * 4;
        #pragma unroll
        for (int tn = 0; tn < 4; ++tn) {
            int col = n0 + wn + tn * 16 + lr;
            if (col >= OUTPUT_DIM) continue;
            int seg = col / HIDDEN;             // const-div -> magic mul
            int off = col - seg * HIDDEN;
            ushort_t* dst = Xp + (long long)seg * M * HPAD + off;
            #pragma unroll
            for (int g = 0; g < 4; ++g) {
                int row = rbase + g;
                if (row < M) dst[(long long)row * HPAD] = bf16_rne(acc[tm][tn][g]);
            }
        }
    }
}

// ---------------------------------------------------------------------------
// Scan helpers. Combined u+v exclusive scan: data = [histm_u | pad0 | histm_v],
// length HISTM_TOT. v-region values include u's total (= NEDGE); scan_add
// subtracts it, so each side ends with its own exclusive offsets.
// ---------------------------------------------------------------------------
__global__ __launch_bounds__(256) void scan1(u32* __restrict__ data, int n,
                                             u32* __restrict__ partials)
{
    __shared__ u32 sh[256];
    int t = threadIdx.x;
    int base = blockIdx.x * 1024 + t * 4;
    u32 x[4];
    #pragma unroll
    for (int k = 0; k < 4; ++k) {
        int idx = base + k;
        x[k] = (idx < n) ? data[idx] : 0u;
    }
    u32 tsum = x[0] + x[1] + x[2] + x[3];
    sh[t] = tsum;
    __syncthreads();
    for (int off = 1; off < 256; off <<= 1) {
        u32 v = (t >= off) ? sh[t - off] : 0u;
        __syncthreads();
        sh[t] += v;
        __syncthreads();
    }
    u32 run = (t > 0) ? sh[t - 1] : 0u;
    if (t == 255) partials[blockIdx.x] = sh[255];
    #pragma unroll
    for (int k = 0; k < 4; ++k) {
        int idx = base + k;
        if (idx < n) data[idx] = run;
        run += x[k];
    }
}

__global__ __launch_bounds__(512) void scan_partials(u32* __restrict__ partials, int n)
{
    __shared__ u32 sh[512];
    int t = threadIdx.x;
    u32 x = (t < n) ? partials[t] : 0u;
    sh[t] = x;
    __syncthreads();
    for (int off = 1; off < 512; off <<= 1) {
        u32 v = (t >= off) ? sh[t - off] : 0u;
        __syncthreads();
        sh[t] += v;
        __syncthreads();
    }
    if (t < n) partials[t] = (t > 0) ? sh[t - 1] : 0u;
}

__global__ __launch_bounds__(256) void scan_add(u32* __restrict__ data, int n,
                                                const u32* __restrict__ partials)
{
    int idx = blockIdx.x * 256 + threadIdx.x;
    if (idx >= n) return;
    u32 adj = (idx >= HISTM_U_ALIGN) ? (u32)NEDGE : 0u;
    data[idx] = data[idx] + partials[idx >> 10] - adj;
}

// ---------------------------------------------------------------------------
// Chunked radix partition (no global atomics, no line-amplified scatter).
// hist_uv: one pass reads rows+cols, builds both bucket-count matrices.
// partition_uv: one pass reads COO once, stages both sides' payloads.
// ---------------------------------------------------------------------------
__global__ __launch_bounds__(256) void hist_uv(
    const int* __restrict__ rows, const int* __restrict__ cols,
    u32* __restrict__ histm_u, u32* __restrict__ histm_v)
{
    __shared__ u32 hu[NB_U];
    __shared__ u32 hv[NB_V];
    const int tid = threadIdx.x;
    const int c = blockIdx.x;
    // zero the alignment pad between the two hist matrices (block 0 only)
    if (c == 0)
        for (int z = HISTM_U_SZ + tid; z < HISTM_U_ALIGN; z += 256) histm_u[z] = 0u;
    for (int b = tid; b < NB_U; b += 256) hu[b] = 0u;
    for (int b = tid; b < NB_V; b += 256) hv[b] = 0u;
    __syncthreads();
    int base = c * CH_E;
    int end = base + CH_E; if (end > NEDGE) end = NEDGE;
    for (int e = base + tid; e < end; e += 256) {
        unsigned i = (unsigned)e / (unsigned)NNZ;
        u32 ku = i * (u32)NUM_USERS + (u32)rows[e];
        u32 kv = i * (u32)NUM_ITEMS + (u32)cols[e];
        atomicAdd(&hu[ku >> 8], 1u);
        atomicAdd(&hv[kv >> 8], 1u);
    }
    __syncthreads();
    for (int b = tid; b < NB_U; b += 256) histm_u[b * NCHUNK + c] = hu[b];
    for (int b = tid; b < NB_V; b += 256) histm_v[b * NCHUNK + c] = hv[b];
}

__global__ __launch_bounds__(256) void partition_uv(
    const int* __restrict__ rows, const int* __restrict__ cols,
    const float* __restrict__ vals,
    const u32* __restrict__ histm_u, const u32* __restrict__ histm_v,
    uint2* __restrict__ buf_u, uint2* __restrict__ buf_v)
{
    __shared__ u32 cu[NB_U];
    __shared__ u32 cv[NB_V];
    const int tid = threadIdx.x;
    const int c = blockIdx.x;
    for (int b = tid; b < NB_U; b += 256) cu[b] = histm_u[b * NCHUNK + c];
    for (int b = tid; b < NB_V; b += 256) cv[b] = histm_v[b * NCHUNK + c];
    __syncthreads();
    int base = c * CH_E;
    int end = base + CH_E; if (end > NEDGE) end = NEDGE;
    for (int e = base + tid; e < end; e += 256) {
        unsigned i = (unsigned)e / (unsigned)NNZ;
        int r = rows[e];
        int col = cols[e];
        u32 vb = __float_as_uint(vals[e]);
        u32 ku = i * (u32)NUM_USERS + (u32)r;
        u32 kv = i * (u32)NUM_ITEMS + (u32)col;
        u32 pu = atomicAdd(&cu[ku >> 8], 1u);
        uint2 eu; eu.x = vb; eu.y = (ku << 14) | (u32)col;
        buf_u[pu] = eu;
        u32 pv = atomicAdd(&cv[kv >> 8], 1u);
        uint2 ev; ev.x = vb; ev.y = (kv << 16) | (u32)r;
        buf_v[pv] = ev;
    }
}

template<int NROWS, int GSHIFT>
__device__ inline void bucket_body(
    int b, const uint2* __restrict__ buf, const u32* __restrict__ histm,
    u32* __restrict__ ptr, uint2* __restrict__ perm,
    u32* cnt, u32* scn)
{
    constexpr int NKEY = NUM_SUPPORT * NROWS;
    constexpr int NB = (NKEY + 255) / 256;
    const int tid = threadIdx.x;
    const u32 key0 = (u32)b << 8;
    const u32 start = histm[b * NCHUNK];
    const u32 bend  = (b + 1 < NB) ? histm[(b + 1) * NCHUNK] : (u32)NEDGE;
    if (b == 0 && tid == 0) ptr[NKEY] = (u32)NEDGE;   // CSR sentinel (fused)
    cnt[tid] = 0u;
    __syncthreads();
    for (u32 j = start + tid; j < bend; j += 256) {
        u32 key = buf[j].y >> GSHIFT;
        atomicAdd(&cnt[key - key0], 1u);
    }
    __syncthreads();
    scn[tid] = cnt[tid];
    __syncthreads();
    for (int off = 1; off < 256; off <<= 1) {
        u32 v = (tid >= off) ? scn[tid - off] : 0u;
        __syncthreads();
        scn[tid] += v;
        __syncthreads();
    }
    u32 myoff = start + scn[tid] - cnt[tid];   // exclusive within bucket
    if (key0 + (u32)tid < (u32)NKEY) ptr[key0 + tid] = myoff;
    __syncthreads();
    cnt[tid] = myoff;                          // becomes running cursor
    __syncthreads();
    for (u32 j = start + tid; j < bend; j += 256) {
        uint2 q = buf[j];
        u32 key = q.y >> GSHIFT;
        u32 p = atomicAdd(&cnt[key - key0], 1u);
        uint2 out;
        out.x = q.x;
        out.y = q.y & ((1u << GSHIFT) - 1u);
        perm[p] = out;
    }
}

__global__ __launch_bounds__(256) void bucket_scatter_uv(
    const uint2* __restrict__ buf_u, const u32* __restrict__ histm_u,
    u32* __restrict__ ptr_u, uint2* __restrict__ perm_u,
    const uint2* __restrict__ buf_v, const u32* __restrict__ histm_v,
    u32* __restrict__ ptr_v, uint2* __restrict__ perm_v)
{
    __shared__ u32 cnt[256];
    __shared__ u32 scn[256];
    if (blockIdx.x < NB_U)
        bucket_body<NUM_USERS, 14>(blockIdx.x, buf_u, histm_u, ptr_u, perm_u, cnt, scn);
    else
        bucket_body<NUM_ITEMS, 16>(blockIdx.x - NB_U, buf_v, histm_v, ptr_v, perm_v, cnt, scn);
}

// ---------------------------------------------------------------------------
// Packed SpMM, 4 rows per wave: each 16-lane group owns one CSR key (row),
// iterates its own edges. Unroll-4 -> 16 row-gathers in flight per wave.
// Each lane gathers 16B (8 bf16 cols) of the 256B packed row -> lanes hold
// the final accumulators directly (no cross-group merge).
// Fused ReLU; per group, lanes 0..12 write the 100 f32.
// ---------------------------------------------------------------------------
template<int NROWS>
__global__ __launch_bounds__(256) void spmm_pack4(
    const u32* __restrict__ ptr,      // [5*NROWS + 1] CSR offsets
    const uint2* __restrict__ perm,   // [NEDGE] (val_bits, gather_idx)
    const ushort_t* __restrict__ Xp,  // [5][nsrc][HPAD] bf16 packed
    float* __restrict__ Z,            // [NROWS][OUTPUT_DIM] f32
    int nsrc)
{
    constexpr int NKEY = NUM_SUPPORT * NROWS;
    int w = (int)((blockIdx.x * 256u + threadIdx.x) >> 6);
    w = __builtin_amdgcn_readfirstlane(w);
    if (w * 4 >= NKEY) return;
    const int lane = threadIdx.x & 63;
    const int g  = lane >> 4;     // group 0..3 -> row w*4+g
    const int sl = lane & 15;     // 8 bf16 cols per lane

    int key = w * 4 + g;          // < NKEY (NKEY divisible by 4)
    int i = key / NROWS;          // support segment
    int r = key - i * NROWS;      // output row
    u32 s = ptr[key];
    u32 e = ptr[key + 1];

    const ushort_t* Xs = Xp + (long long)i * nsrc * HPAD + sl * 8;

    // wave-max trip count (groups differ only in lane bits 4..5)
    u32 m = e - s;
    { u32 t = (u32)__shfl_xor((int)m, 16); m = m > t ? m : t; }
    { u32 t = (u32)__shfl_xor((int)m, 32); m = m > t ? m : t; }
    int iters = (int)((m + 3) >> 2);

    float a0 = 0.f, a1 = 0.f, a2 = 0.f, a3 = 0.f;
    float a4 = 0.f, a5 = 0.f, a6 = 0.f, a7 = 0.f;
    u32 k = s;
    for (int it = 0; it < iters; ++it) {
        bool p0 = k < e, p1 = (k + 1) < e, p2 = (k + 2) < e, p3 = (k + 3) < e;
        u32 j0 = p0 ? k : 0u;
        u32 j1 = p1 ? (k + 1) : 0u;
        u32 j2 = p2 ? (k + 2) : 0u;
        u32 j3 = p3 ? (k + 3) : 0u;
        uint2 q0 = perm[j0], q1 = perm[j1], q2 = perm[j2], q3 = perm[j3];
        float v0 = p0 ? __uint_as_float(q0.x) : 0.f;
        float v1 = p1 ? __uint_as_float(q1.x) : 0.f;
        float v2 = p2 ? __uint_as_float(q2.x) : 0.f;
        float v3 = p3 ? __uint_as_float(q3.x) : 0.f;
        uint4 w0 = *(const uint4*)(Xs + ((long long)q0.y << 7));
        uint4 w1 = *(const uint4*)(Xs + ((long long)q1.y << 7));
        uint4 w2 = *(const uint4*)(Xs + ((long long)q2.y << 7));
        uint4 w3 = *(const uint4*)(Xs + ((long long)q3.y << 7));
        a0 += v0 * bf16_lo_f32(w0.x) + v1 * bf16_lo_f32(w1.x)
            + v2 * bf16_lo_f32(w2.x) + v3 * bf16_lo_f32(w3.x);
        a1 += v0 * bf16_hi_f32(w0.x) + v1 * bf16_hi_f32(w1.x)
            + v2 * bf16_hi_f32(w2.x) + v3 * bf16_hi_f32(w3.x);
        a2 += v0 * bf16_lo_f32(w0.y) + v1 * bf16_lo_f32(w1.y)
            + v2 * bf16_lo_f32(w2.y) + v3 * bf16_lo_f32(w3.y);
        a3 += v0 * bf16_hi_f32(w0.y) + v1 * bf16_hi_f32(w1.y)
            + v2 * bf16_hi_f32(w2.y) + v3 * bf16_hi_f32(w3.y);
        a4 += v0 * bf16_lo_f32(w0.z) + v1 * bf16_lo_f32(w1.z)
            + v2 * bf16_lo_f32(w2.z) + v3 * bf16_lo_f32(w3.z);
        a5 += v0 * bf16_hi_f32(w0.z) + v1 * bf16_hi_f32(w1.z)
            + v2 * bf16_hi_f32(w2.z) + v3 * bf16_hi_f32(w3.z);
        a6 += v0 * bf16_lo_f32(w0.w) + v1 * bf16_lo_f32(w1.w)
            + v2 * bf16_lo_f32(w2.w) + v3 * bf16_lo_f32(w3.w);
        a7 += v0 * bf16_hi_f32(w0.w) + v1 * bf16_hi_f32(w1.w)
            + v2 * bf16_hi_f32(w2.w) + v3 * bf16_hi_f32(w3.w);
        k += 4;
    }

    if (sl < 13) {
        float* zp = Z + (long long)r * OUTPUT_DIM + i * HIDDEN + sl * 8;
        float4 o0;
        o0.x = a0 > 0.f ? a0 : 0.f;
        o0.y = a1 > 0.f ? a1 : 0.f;
        o0.z = a2 > 0.f ? a2 : 0.f;
        o0.w = a3 > 0.f ? a3 : 0.f;
        *(float4*)zp = o0;                       // cols 8*sl .. +3
        if (sl < 12) {
            float4 o1;
            o1.x = a4 > 0.f ? a4 : 0.f;
            o1.y = a5 > 0.f ? a5 : 0.f;
            o1.z = a6 > 0.f ? a6 : 0.f;
            o1.w = a7 > 0.f ? a7 : 0.f;
            *(float4*)(zp + 4) = o1;             // cols 8*sl+4 .. +7
        }
    }
}

// ---------------------------------------------------------------------------
// Fallback path: f32 GEMM + COO atomic scatter (only if ws too small)
// ---------------------------------------------------------------------------
#define TM 64
#define TN 64
#define TK 16

__global__ __launch_bounds__(256) void gemm_f32(
    const float* __restrict__ A, const float* __restrict__ B,
    float* __restrict__ C, int M, int N, int K, int ldc)
{
    __shared__ float Asl[TK][TM + 4];
    __shared__ float Bsl[TK][TN + 4];
    const int tid = threadIdx.x;
    const int tx  = tid & 15;
    const int ty  = tid >> 4;
    const int row0 = blockIdx.x * TM;
    const int col0 = blockIdx.y * TN;
    float acc[4][4] = {};
    for (int k0 = 0; k0 < K; k0 += TK) {
        #pragma unroll
        for (int it = 0; it < (TM * TK) / 256; ++it) {
            int idx = tid + it * 256;
            int m = idx >> 4, kk = idx & 15, gr = row0 + m;
            Asl[kk][m] = (gr < M) ? A[(long long)gr * K + (k0 + kk)] : 0.f;
        }
        #pragma unroll
        for (int it = 0; it < (TK * TN) / 256; ++it) {
            int idx = tid + it * 256;
            int kk = idx >> 6, n = idx & 63, gc = col0 + n;
            Bsl[kk][n] = (gc < N) ? B[(long long)(k0 + kk) * N + gc] : 0.f;
        }
        __syncthreads();
        #pragma unroll
        for (int kk = 0; kk < TK; ++kk) {
            float a[4], b[4];
            #pragma unroll
            for (int u = 0; u < 4; ++u) a[u] = Asl[kk][ty * 4 + u];
            #pragma unroll
            for (int v = 0; v < 4; ++v) b[v] = Bsl[kk][tx * 4 + v];
            #pragma unroll
            for (int u = 0; u < 4; ++u)
                #pragma unroll
                for (int v = 0; v < 4; ++v)
                    acc[u][v] += a[u] * b[v];
        }
        __syncthreads();
    }
    #pragma unroll
    for (int u = 0; u < 4; ++u) {
        int gr = row0 + ty * 4 + u;
        if (gr >= M) continue;
        #pragma unroll
        for (int v = 0; v < 4; ++v) {
            int gc = col0 + tx * 4 + v;
            if (gc < N) C[(long long)gr * ldc + gc] = acc[u][v];
        }
    }
}

__global__ __launch_bounds__(256) void scatter_edges(
    const float* __restrict__ sup_vals,
    const int*   __restrict__ sup_rows,
    const int*   __restrict__ sup_cols,
    const float* __restrict__ XU, const float* __restrict__ XV,
    float* __restrict__ z_u, float* __restrict__ z_v)
{
    const unsigned t = blockIdx.x * 256u + threadIdx.x;
    const unsigned total = (unsigned)NEDGE * HIDDEN;
    if (t >= total) return;
    const unsigned j  = t % HIDDEN;
    const unsigned eg = t / HIDDEN;
    const unsigned i  = eg / NNZ;
    const float val = sup_vals[eg];
    const int   r   = sup_rows[eg];
    const int   c   = sup_cols[eg];
    const int   colOff = i * HIDDEN + j;
    atomicAdd(&z_u[(long long)r * OUTPUT_DIM + colOff],
              val * XV[(long long)c * NPAD + colOff]);
    atomicAdd(&z_v[(long long)c * OUTPUT_DIM + colOff],
              val * XU[(long long)r * NPAD + colOff]);
}

__global__ __launch_bounds__(256) void relu_inplace(float4* __restrict__ p, int n4)
{
    int t = blockIdx.x * 256 + threadIdx.x;
    if (t >= n4) return;
    float4 v = p[t];
    v.x = v.x > 0.f ? v.x : 0.f;
    v.y = v.y > 0.f ? v.y : 0.f;
    v.z = v.z > 0.f ? v.z : 0.f;
    v.w = v.w > 0.f ? v.w : 0.f;
    p[t] = v;
}

extern "C" void kernel_launch(void* const* d_in, const int* in_sizes, int n_in,
                              void* d_out, int out_size, void* d_ws, size_t ws_size,
                              hipStream_t stream)
{
    const float* x_u      = (const float*)d_in[0];
    const float* x_v      = (const float*)d_in[1];
    const float* W        = (const float*)d_in[2];
    const float* sup_vals = (const float*)d_in[3];
    const int*   sup_rows = (const int*)d_in[4];
    const int*   sup_cols = (const int*)d_in[5];

    float* z_u = (float*)d_out;
    float* z_v = z_u + (long long)NUM_USERS * OUTPUT_DIM;

    const long long NU = (long long)NUM_USERS * 512;   // bf16 input elems (25.6M)
    const long long NV = (long long)NUM_ITEMS * 512;   //  5.12M
    const long long PU = (long long)NUM_SUPPORT * NUM_USERS * HPAD;  // 32M
    const long long PV = (long long)NUM_SUPPORT * NUM_ITEMS * HPAD;  // 6.4M
    const int NRU = NUM_SUPPORT * NUM_USERS;  // 250000 keys (u side)
    const int NRV = NUM_SUPPORT * NUM_ITEMS;  //  50000 keys (v side)

    // ---- full-path workspace layout (~140 MB) ----
    ushort_t* Xp_u  = (ushort_t*)d_ws;        // packed gemm out [5][50000][128]
    ushort_t* Xp_v  = Xp_u + PU;              // packed gemm out [5][10000][128]
    ushort_t* xu_in = Xp_v + PV;              // bf16(x_u); reused as scratch post-GEMM
    ushort_t* xv_in = xu_in + NU;             // bf16(x_v)
    ushort_t* WbT   = xv_in + NV;             // bf16 W^T padded [512][512]
    u32* row_ptr_u  = (u32*)(WbT + 512 * 512);     // [NRU+1]
    u32* col_ptr_v  = row_ptr_u + (NRU + 1);       // [NRV+1]
    u32* partials   = col_ptr_v + (NRV + 1);       // [512]
    size_t need_full = ((char*)(partials + 512)) - ((char*)d_ws);

    // scratch aliases inside xu_in (only used AFTER both GEMMs consumed it):
    // buf_v 16MB + histm (combined, 1.15MB) + perm_u 16MB + perm_v 16MB
    //   = 49.3MB <= 51.2MB.   buf_u (16MB) lives in the z_u output region
    //   (dead until spmm_pack4<u> overwrites all of z_u at the end).
    uint2* buf_v    = (uint2*)xu_in;               // [NEDGE] phase-B staging (v)
    u32*   histm_u  = (u32*)(buf_v + NEDGE);       // [HISTM_U_ALIGN] (incl. zero pad)
    u32*   histm_v  = histm_u + HISTM_U_ALIGN;     // [HISTM_V_SZ]
    uint2* perm_u   = (uint2*)(histm_v + HISTM_V_SZ);   // [NEDGE] (val,gidx)
    uint2* perm_v   = perm_u + NEDGE;                   // [NEDGE]
    uint2* buf_u    = (uint2*)z_u;                 // [NEDGE] staging (u) in d_out

    dim3 blk(256);

    if (ws_size >= need_full) {
        // ---- dense projections (bf16 MFMA, packed epilogue) ----
        {
            int na4 = (int)(NU / 4), nb4 = (int)(NV / 4);
            cvt_bf16_2<<<(na4 + nb4 + 255) / 256, blk, 0, stream>>>(
                (const float4*)x_u, (const float4*)x_v,
                (ushort4*)xu_in, (ushort4*)xv_in, na4, nb4);
        }
        make_WbT<<<(512 * 512) / 256, blk, 0, stream>>>(W, WbT);
        gemm_mfma_bf16<<<dim3((NUM_USERS + BM - 1) / BM, 512 / BN), blk, 0, stream>>>(
            xu_in, WbT, Xp_u, NUM_USERS);
        gemm_mfma_bf16<<<dim3((NUM_ITEMS + BM - 1) / BM, 512 / BN), blk, 0, stream>>>(
            xv_in, WbT, Xp_v, NUM_ITEMS);

        // xu_in is now dead -> buf_v/histm/perm scratch is live.
        // ---- fused chunk histograms (reads rows+cols once) ----
        hist_uv<<<NCHUNK, blk, 0, stream>>>(sup_rows, sup_cols, histm_u, histm_v);

        // ---- combined exclusive scan over [histm_u | pad | histm_v] ----
        {
            int nb = (HISTM_TOT + 1023) / 1024;                 // 281 <= 512
            scan1<<<nb, blk, 0, stream>>>(histm_u, HISTM_TOT, partials);
            scan_partials<<<1, dim3(512), 0, stream>>>(partials, nb);
            scan_add<<<(HISTM_TOT + 255) / 256, blk, 0, stream>>>(
                histm_u, HISTM_TOT, partials);
        }

        // ---- fused partition (reads COO once, stages both sides) ----
        partition_uv<<<NCHUNK, blk, 0, stream>>>(
            sup_rows, sup_cols, sup_vals, histm_u, histm_v, buf_u, buf_v);

        // ---- fused bucket scatter (u blocks then v blocks) ----
        bucket_scatter_uv<<<NB_U + NB_V, blk, 0, stream>>>(
            buf_u, histm_u, row_ptr_u, perm_u,
            buf_v, histm_v, col_ptr_v, perm_v);

        // ---- SpMM (fused ReLU), 4 rows per wave, unroll-4 ----
        spmm_pack4<NUM_USERS><<<((NRU / 4) * 64) / 256, blk, 0, stream>>>(
            row_ptr_u, perm_u, Xp_v, z_u, NUM_ITEMS);
        spmm_pack4<NUM_ITEMS><<<((NRV / 4) * 64) / 256, blk, 0, stream>>>(
            col_ptr_v, perm_v, Xp_u, z_v, NUM_USERS);
    } else {
        // ---- fallback: f32 GEMM + atomic scatter ----
        float* XU = (float*)d_ws;
        float* XV = XU + (long long)NUM_USERS * NPAD;
        gemm_f32<<<dim3((NUM_USERS + TM - 1) / TM, (OUTPUT_DIM + TN - 1) / TN),
                   blk, 0, stream>>>(x_u, W, XU, NUM_USERS, OUTPUT_DIM, INPUT_DIM, NPAD);
        gemm_f32<<<dim3((NUM_ITEMS + TM - 1) / TM, (OUTPUT_DIM + TN - 1) / TN),
                   blk, 0, stream>>>(x_v, W, XV, NUM_ITEMS, OUTPUT_DIM, INPUT_DIM, NPAD);
        hipMemsetAsync(d_out, 0, (size_t)out_size * sizeof(float), stream);
        unsigned total = (unsigned)NEDGE * HIDDEN;
        scatter_edges<<<(total + 255u) / 256u, blk, 0, stream>>>(
            sup_vals, sup_rows, sup_cols, XU, XV, z_u, z_v);
        int n4 = out_size / 4;
        relu_inplace<<<(n4 + 255) / 256, blk, 0, stream>>>((float4*)d_out, n4);
    }
}

// Round 6
// 513.696 us; speedup vs baseline: 2.3397x; 1.0108x over previous
//
#include <hip/hip_runtime.h>

// Problem constants (match reference)
#define NUM_USERS   50000
#define NUM_ITEMS   10000
#define NUM_SUPPORT 5
#define INPUT_DIM   512      // K
#define OUTPUT_DIM  500
#define NPAD        512      // padded output-dim stride (fallback path only)
#define HIDDEN      100      // OUTPUT_DIM / NUM_SUPPORT
#define HPAD        128      // packed per-support row: 100 bf16 padded to 128 (256B)
#define NNZ         400000
#define NEDGE       (NUM_SUPPORT * NNZ)     // 2,000,000

// radix-partition parameters
#define CH_E        8192                         // edges per chunk
#define NCHUNK      ((NEDGE + CH_E - 1) / CH_E)  // 245
#define NB_U        ((NUM_SUPPORT * NUM_USERS + 255) / 256)   // 977
// v-side key space is rblock-expanded: knew = (i*NUM_ITEMS+col)*4 + rb, rb=r/12500
#define NKEY_V2     (NUM_SUPPORT * NUM_ITEMS * 4)            // 200000
#define NB_V2       ((NKEY_V2 + 255) / 256)                  // 782
#define HISTM_U_SZ  (NB_U * NCHUNK)              // 239365
#define HISTM_U_ALIGN 239616                     // 234*1024: pad so v region is block-aligned
#define HISTM_V_SZ  (NB_V2 * NCHUNK)             // 191590
#define HISTM_TOT   (HISTM_U_ALIGN + HISTM_V_SZ) // 431206 (combined scan length)

typedef unsigned int u32;
typedef unsigned short ushort_t;
typedef __attribute__((ext_vector_type(4))) float f32x4;
typedef __attribute__((ext_vector_type(8))) short bf16x8;   // 8 bf16 in 4 VGPRs

// async global->LDS, 16B per lane. LDS side must be wave-uniform base + lane*16.
#define GLDS(g, l) __builtin_amdgcn_global_load_lds( \
    (const __attribute__((address_space(1))) unsigned int*)(g), \
    (__attribute__((address_space(3))) unsigned int*)(l), 16, 0, 0)

__device__ inline ushort_t bf16_rne(float f) {
    u32 u = __float_as_uint(f);
    u32 r = (u + 0x7FFFu + ((u >> 16) & 1u)) >> 16;
    return (ushort_t)r;
}
__device__ inline float bf16_lo_f32(u32 w) { return __uint_as_float(w << 16); }
__device__ inline float bf16_hi_f32(u32 w) { return __uint_as_float(w & 0xFFFF0000u); }

// rblock of a user id (4 blocks of 12500 -> 3.2MB gather segments)
__device__ inline u32 rb3(u32 r) {
    return (r >= 12500u ? 1u : 0u) + (r >= 25000u ? 1u : 0u) + (r >= 37500u ? 1u : 0u);
}

// bijective XCD-aware block swizzle (m204 form): each XCD gets a contiguous chunk
__device__ inline int xcd_swizzle(int bid, int nwg) {
    int q = nwg >> 3, rmd = nwg & 7;
    int xcd = bid & 7, idx = bid >> 3;
    int base = (xcd < rmd) ? xcd * (q + 1) : rmd * (q + 1) + (xcd - rmd) * q;
    return base + idx;
}

// ---------------------------------------------------------------------------
// f32 -> bf16 conversion, both tensors in one launch
// ---------------------------------------------------------------------------
__global__ __launch_bounds__(256) void cvt_bf16_2(
    const float4* __restrict__ a, const float4* __restrict__ b,
    ushort4* __restrict__ oa, ushort4* __restrict__ ob, int na4, int nb4)
{
    int t = blockIdx.x * 256 + threadIdx.x;
    const float4* src;
    ushort4* dst;
    int idx;
    if (t < na4) { src = a; dst = oa; idx = t; }
    else { idx = t - na4; if (idx >= nb4) return; src = b; dst = ob; }
    float4 v = src[idx];
    ushort4 o;
    o.x = bf16_rne(v.x); o.y = bf16_rne(v.y);
    o.z = bf16_rne(v.z); o.w = bf16_rne(v.w);
    dst[idx] = o;
}

// WbT[n][k] = W[k][n] (bf16), n padded 500->512 with zeros. 512x512.
__global__ __launch_bounds__(256) void make_WbT(
    const float* __restrict__ W, ushort_t* __restrict__ WbT)
{
    int t = blockIdx.x * 256 + threadIdx.x;
    int n = t >> 9, k = t & 511;
    float v = (n < OUTPUT_DIM) ? W[k * OUTPUT_DIM + n] : 0.f;
    WbT[t] = bf16_rne(v);
}

// ---------------------------------------------------------------------------
// MFMA bf16 GEMM: Xp[seg][M][128](bf16) = packed A @ BT^T
// 128x128 tile, BK=32, 256 thr (4 waves, each 64x64 = 4x4 tiles of 16x16x32).
// Epilogue writes support-major packed layout: col c -> seg=c/100, off=c%100.
// ---------------------------------------------------------------------------
#define BM 128
#define BN 128
#define BK 32

__global__ __launch_bounds__(256) void gemm_mfma_bf16(
    const ushort_t* __restrict__ A,    // [M][512] bf16
    const ushort_t* __restrict__ BT,   // [512][512] bf16 (BT[n][k])
    ushort_t* __restrict__ Xp,         // [5][M][HPAD] bf16 packed
    int M)
{
    const int K = INPUT_DIM;
    __shared__ ushort_t As[BM * BK];   // [m][k], 64B rows
    __shared__ ushort_t Bs[BN * BK];   // [n][k], 64B rows

    const int tid  = threadIdx.x;
    const int wave = tid >> 6;
    const int lane = tid & 63;
    const int quad = lane >> 4;
    const int lr   = lane & 15;
    const int m0 = blockIdx.x * BM;
    const int n0 = blockIdx.y * BN;
    const int wm = (wave >> 1) * 64;
    const int wn = (wave & 1) * 64;

    f32x4 acc[4][4] = {};

    for (int k0 = 0; k0 < K; k0 += BK) {
        #pragma unroll
        for (int h = 0; h < 2; ++h) {
            int o   = tid * 16 + h * 4096;
            int row = o >> 6;
            int byt = o & 63;
            int gr  = m0 + row; if (gr >= M) gr = M - 1;   // clamp (masked at store)
            GLDS((const char*)A + ((long long)gr * K + k0) * 2 + byt, (char*)As + o);
        }
        #pragma unroll
        for (int h = 0; h < 2; ++h) {
            int o   = tid * 16 + h * 4096;
            int row = o >> 6;
            int byt = o & 63;
            GLDS((const char*)BT + ((long long)(n0 + row) * K + k0) * 2 + byt, (char*)Bs + o);
        }
        asm volatile("s_waitcnt vmcnt(0)" ::: "memory");
        __syncthreads();

        bf16x8 af[4], bfr[4];
        #pragma unroll
        for (int tm = 0; tm < 4; ++tm)
            af[tm] = *(const bf16x8*)(As + (wm + tm * 16 + lr) * BK + quad * 8);
        #pragma unroll
        for (int tn = 0; tn < 4; ++tn)
            bfr[tn] = *(const bf16x8*)(Bs + (wn + tn * 16 + lr) * BK + quad * 8);
        #pragma unroll
        for (int tm = 0; tm < 4; ++tm)
            #pragma unroll
            for (int tn = 0; tn < 4; ++tn)
                acc[tm][tn] = __builtin_amdgcn_mfma_f32_16x16x32_bf16(
                    af[tm], bfr[tn], acc[tm][tn], 0, 0, 0);
        __syncthreads();
    }

    // epilogue: C/D layout col=lane&15, row=quad*4+reg; scatter into packed Xp
    #pragma unroll
    for (int tm = 0; tm < 4; ++tm) {
        int rbase = m0 + wm + tm * 16 + quad * 4;
        #pragma unroll
        for (int tn = 0; tn < 4; ++tn) {
            int col = n0 + wn + tn * 16 + lr;
            if (col >= OUTPUT_DIM) continue;
            int seg = col / HIDDEN;             // const-div -> magic mul
            int off = col - seg * HIDDEN;
            ushort_t* dst = Xp + (long long)seg * M * HPAD + off;
            #pragma unroll
            for (int g = 0; g < 4; ++g) {
                int row = rbase + g;
                if (row < M) dst[(long long)row * HPAD] = bf16_rne(acc[tm][tn][g]);
            }
        }
    }
}

// ---------------------------------------------------------------------------
// Scan helpers. Combined u+v exclusive scan: data = [histm_u | pad0 | histm_v],
// length HISTM_TOT. v-region values include u's total (= NEDGE); scan_add
// subtracts it, so each side ends with its own exclusive offsets.
// ---------------------------------------------------------------------------
__global__ __launch_bounds__(256) void scan1(u32* __restrict__ data, int n,
                                             u32* __restrict__ partials)
{
    __shared__ u32 sh[256];
    int t = threadIdx.x;
    int base = blockIdx.x * 1024 + t * 4;
    u32 x[4];
    #pragma unroll
    for (int k = 0; k < 4; ++k) {
        int idx = base + k;
        x[k] = (idx < n) ? data[idx] : 0u;
    }
    u32 tsum = x[0] + x[1] + x[2] + x[3];
    sh[t] = tsum;
    __syncthreads();
    for (int off = 1; off < 256; off <<= 1) {
        u32 v = (t >= off) ? sh[t - off] : 0u;
        __syncthreads();
        sh[t] += v;
        __syncthreads();
    }
    u32 run = (t > 0) ? sh[t - 1] : 0u;
    if (t == 255) partials[blockIdx.x] = sh[255];
    #pragma unroll
    for (int k = 0; k < 4; ++k) {
        int idx = base + k;
        if (idx < n) data[idx] = run;
        run += x[k];
    }
}

__global__ __launch_bounds__(512) void scan_partials(u32* __restrict__ partials, int n)
{
    __shared__ u32 sh[512];
    int t = threadIdx.x;
    u32 x = (t < n) ? partials[t] : 0u;
    sh[t] = x;
    __syncthreads();
    for (int off = 1; off < 512; off <<= 1) {
        u32 v = (t >= off) ? sh[t - off] : 0u;
        __syncthreads();
        sh[t] += v;
        __syncthreads();
    }
    if (t < n) partials[t] = (t > 0) ? sh[t - 1] : 0u;
}

__global__ __launch_bounds__(256) void scan_add(u32* __restrict__ data, int n,
                                                const u32* __restrict__ partials)
{
    int idx = blockIdx.x * 256 + threadIdx.x;
    if (idx >= n) return;
    u32 adj = (idx >= HISTM_U_ALIGN) ? (u32)NEDGE : 0u;
    data[idx] = data[idx] + partials[idx >> 10] - adj;
}

// ---------------------------------------------------------------------------
// Chunked radix partition (no global atomics, no line-amplified scatter).
// u-side key: ku = i*NUM_USERS + row           (bucket = ku>>8)
// v-side key: knew = (i*NUM_ITEMS+col)*4 + rb3(row)  (bucket = knew>>8)
//   -> edges of one col are grouped by user-rblock for gather L2 locality;
//      the 4 rb runs are adjacent, so spmm reads ptr[4k]..ptr[4k+4].
// Payloads: u: (ku<<14)|col ; v: (kv16<<16)|row  (knew recomputed from fields).
// ---------------------------------------------------------------------------
__global__ __launch_bounds__(256) void hist_uv(
    const int* __restrict__ rows, const int* __restrict__ cols,
    u32* __restrict__ histm_u, u32* __restrict__ histm_v)
{
    __shared__ u32 hu[NB_U];
    __shared__ u32 hv[NB_V2];
    const int tid = threadIdx.x;
    const int c = blockIdx.x;
    // zero the alignment pad between the two hist matrices (block 0 only)
    if (c == 0)
        for (int z = HISTM_U_SZ + tid; z < HISTM_U_ALIGN; z += 256) histm_u[z] = 0u;
    for (int b = tid; b < NB_U; b += 256) hu[b] = 0u;
    for (int b = tid; b < NB_V2; b += 256) hv[b] = 0u;
    __syncthreads();
    int base = c * CH_E;
    int end = base + CH_E; if (end > NEDGE) end = NEDGE;
    for (int e = base + tid; e < end; e += 256) {
        unsigned i = (unsigned)e / (unsigned)NNZ;
        u32 r = (u32)rows[e];
        u32 ku = i * (u32)NUM_USERS + r;
        u32 knew = (i * (u32)NUM_ITEMS + (u32)cols[e]) * 4u + rb3(r);
        atomicAdd(&hu[ku >> 8], 1u);
        atomicAdd(&hv[knew >> 8], 1u);
    }
    __syncthreads();
    for (int b = tid; b < NB_U; b += 256) histm_u[b * NCHUNK + c] = hu[b];
    for (int b = tid; b < NB_V2; b += 256) histm_v[b * NCHUNK + c] = hv[b];
}

__global__ __launch_bounds__(256) void partition_uv(
    const int* __restrict__ rows, const int* __restrict__ cols,
    const float* __restrict__ vals,
    const u32* __restrict__ histm_u, const u32* __restrict__ histm_v,
    uint2* __restrict__ buf_u, uint2* __restrict__ buf_v)
{
    __shared__ u32 cu[NB_U];
    __shared__ u32 cv[NB_V2];
    const int tid = threadIdx.x;
    const int c = blockIdx.x;
    for (int b = tid; b < NB_U; b += 256) cu[b] = histm_u[b * NCHUNK + c];
    for (int b = tid; b < NB_V2; b += 256) cv[b] = histm_v[b * NCHUNK + c];
    __syncthreads();
    int base = c * CH_E;
    int end = base + CH_E; if (end > NEDGE) end = NEDGE;
    for (int e = base + tid; e < end; e += 256) {
        unsigned i = (unsigned)e / (unsigned)NNZ;
        u32 r = (u32)rows[e];
        u32 col = (u32)cols[e];
        u32 vb = __float_as_uint(vals[e]);
        u32 ku = i * (u32)NUM_USERS + r;
        u32 kv16 = i * (u32)NUM_ITEMS + col;
        u32 knew = kv16 * 4u + rb3(r);
        u32 pu = atomicAdd(&cu[ku >> 8], 1u);
        uint2 eu; eu.x = vb; eu.y = (ku << 14) | col;
        buf_u[pu] = eu;
        u32 pv = atomicAdd(&cv[knew >> 8], 1u);
        uint2 ev; ev.x = vb; ev.y = (kv16 << 16) | r;
        buf_v[pv] = ev;
    }
}

__device__ inline void bucket_body_u(
    int b, const uint2* __restrict__ buf, const u32* __restrict__ histm,
    u32* __restrict__ ptr, uint2* __restrict__ perm,
    u32* cnt, u32* scn)
{
    constexpr int NKEY = NUM_SUPPORT * NUM_USERS;
    constexpr int NB = NB_U;
    const int tid = threadIdx.x;
    const u32 key0 = (u32)b << 8;
    const u32 start = histm[b * NCHUNK];
    const u32 bend  = (b + 1 < NB) ? histm[(b + 1) * NCHUNK] : (u32)NEDGE;
    if (b == 0 && tid == 0) ptr[NKEY] = (u32)NEDGE;   // CSR sentinel
    cnt[tid] = 0u;
    __syncthreads();
    for (u32 j = start + tid; j < bend; j += 256) {
        u32 key = buf[j].y >> 14;
        atomicAdd(&cnt[key - key0], 1u);
    }
    __syncthreads();
    scn[tid] = cnt[tid];
    __syncthreads();
    for (int off = 1; off < 256; off <<= 1) {
        u32 v = (tid >= off) ? scn[tid - off] : 0u;
        __syncthreads();
        scn[tid] += v;
        __syncthreads();
    }
    u32 myoff = start + scn[tid] - cnt[tid];
    if (key0 + (u32)tid < (u32)NKEY) ptr[key0 + tid] = myoff;
    __syncthreads();
    cnt[tid] = myoff;
    __syncthreads();
    for (u32 j = start + tid; j < bend; j += 256) {
        uint2 q = buf[j];
        u32 key = q.y >> 14;
        u32 p = atomicAdd(&cnt[key - key0], 1u);
        uint2 out;
        out.x = q.x;
        out.y = q.y & 0x3FFFu;
        perm[p] = out;
    }
}

__device__ inline void bucket_body_v(
    int b, const uint2* __restrict__ buf, const u32* __restrict__ histm,
    u32* __restrict__ ptr, uint2* __restrict__ perm,
    u32* cnt, u32* scn)
{
    constexpr int NKEY = NKEY_V2;
    constexpr int NB = NB_V2;
    const int tid = threadIdx.x;
    const u32 key0 = (u32)b << 8;
    const u32 start = histm[b * NCHUNK];
    const u32 bend  = (b + 1 < NB) ? histm[(b + 1) * NCHUNK] : (u32)NEDGE;
    if (b == 0 && tid == 0) ptr[NKEY] = (u32)NEDGE;   // CSR sentinel
    cnt[tid] = 0u;
    __syncthreads();
    for (u32 j = start + tid; j < bend; j += 256) {
        u32 y = buf[j].y;
        u32 key = (y >> 16) * 4u + rb3(y & 0xFFFFu);
        atomicAdd(&cnt[key - key0], 1u);
    }
    __syncthreads();
    scn[tid] = cnt[tid];
    __syncthreads();
    for (int off = 1; off < 256; off <<= 1) {
        u32 v = (tid >= off) ? scn[tid - off] : 0u;
        __syncthreads();
        scn[tid] += v;
        __syncthreads();
    }
    u32 myoff = start + scn[tid] - cnt[tid];
    if (key0 + (u32)tid < (u32)NKEY) ptr[key0 + tid] = myoff;
    __syncthreads();
    cnt[tid] = myoff;
    __syncthreads();
    for (u32 j = start + tid; j < bend; j += 256) {
        uint2 q = buf[j];
        u32 key = (q.y >> 16) * 4u + rb3(q.y & 0xFFFFu);
        u32 p = atomicAdd(&cnt[key - key0], 1u);
        uint2 out;
        out.x = q.x;
        out.y = q.y & 0xFFFFu;
        perm[p] = out;
    }
}

__global__ __launch_bounds__(256) void bucket_scatter_uv(
    const uint2* __restrict__ buf_u, const u32* __restrict__ histm_u,
    u32* __restrict__ ptr_u, uint2* __restrict__ perm_u,
    const uint2* __restrict__ buf_v, const u32* __restrict__ histm_v,
    u32* __restrict__ ptr_v, uint2* __restrict__ perm_v)
{
    __shared__ u32 cnt[256];
    __shared__ u32 scn[256];
    if (blockIdx.x < NB_U)
        bucket_body_u(blockIdx.x, buf_u, histm_u, ptr_u, perm_u, cnt, scn);
    else
        bucket_body_v(blockIdx.x - NB_U, buf_v, histm_v, ptr_v, perm_v, cnt, scn);
}

// ---------------------------------------------------------------------------
// Packed SpMM, 4 rows per wave: each 16-lane group owns one output key,
// iterating ptr[key*PSTR] .. ptr[(key+1)*PSTR] (PSTR=4 concatenates the
// 4 rblock runs of a v-col). Unroll-4 -> 16 row-gathers in flight per wave.
// Each lane gathers 16B (8 bf16 cols) of the 256B packed row; lanes hold the
// final accumulators directly. Fused ReLU; lanes 0..12 write the 100 f32.
// XCD-swizzled blockIdx for per-XCD gather locality.
// ---------------------------------------------------------------------------
template<int NROWS, int PSTR>
__global__ __launch_bounds__(256) void spmm_pack4(
    const u32* __restrict__ ptr,      // [5*NROWS*PSTR + 1] CSR offsets
    const uint2* __restrict__ perm,   // [NEDGE] (val_bits, gather_idx)
    const ushort_t* __restrict__ Xp,  // [5][nsrc][HPAD] bf16 packed
    float* __restrict__ Z,            // [NROWS][OUTPUT_DIM] f32
    int nsrc)
{
    constexpr int NKEY = NUM_SUPPORT * NROWS;
    int bid = xcd_swizzle(blockIdx.x, gridDim.x);
    int w = bid * 4 + (int)(threadIdx.x >> 6);
    w = __builtin_amdgcn_readfirstlane(w);
    if (w * 4 >= NKEY) return;
    const int lane = threadIdx.x & 63;
    const int g  = lane >> 4;     // group 0..3 -> key w*4+g
    const int sl = lane & 15;     // 8 bf16 cols per lane

    int key = w * 4 + g;          // < NKEY (NKEY divisible by 4)
    int i = key / NROWS;          // support segment
    int r = key - i * NROWS;      // output row
    u32 s = ptr[key * PSTR];
    u32 e = ptr[(key + 1) * PSTR];

    const ushort_t* Xs = Xp + (long long)i * nsrc * HPAD + sl * 8;

    // wave-max trip count (groups differ only in lane bits 4..5)
    u32 m = e - s;
    { u32 t = (u32)__shfl_xor((int)m, 16); m = m > t ? m : t; }
    { u32 t = (u32)__shfl_xor((int)m, 32); m = m > t ? m : t; }
    int iters = (int)((m + 3) >> 2);

    float a0 = 0.f, a1 = 0.f, a2 = 0.f, a3 = 0.f;
    float a4 = 0.f, a5 = 0.f, a6 = 0.f, a7 = 0.f;
    u32 k = s;
    for (int it = 0; it < iters; ++it) {
        bool p0 = k < e, p1 = (k + 1) < e, p2 = (k + 2) < e, p3 = (k + 3) < e;
        u32 j0 = p0 ? k : 0u;
        u32 j1 = p1 ? (k + 1) : 0u;
        u32 j2 = p2 ? (k + 2) : 0u;
        u32 j3 = p3 ? (k + 3) : 0u;
        uint2 q0 = perm[j0], q1 = perm[j1], q2 = perm[j2], q3 = perm[j3];
        float v0 = p0 ? __uint_as_float(q0.x) : 0.f;
        float v1 = p1 ? __uint_as_float(q1.x) : 0.f;
        float v2 = p2 ? __uint_as_float(q2.x) : 0.f;
        float v3 = p3 ? __uint_as_float(q3.x) : 0.f;
        uint4 w0 = *(const uint4*)(Xs + ((long long)q0.y << 7));
        uint4 w1 = *(const uint4*)(Xs + ((long long)q1.y << 7));
        uint4 w2 = *(const uint4*)(Xs + ((long long)q2.y << 7));
        uint4 w3 = *(const uint4*)(Xs + ((long long)q3.y << 7));
        a0 += v0 * bf16_lo_f32(w0.x) + v1 * bf16_lo_f32(w1.x)
            + v2 * bf16_lo_f32(w2.x) + v3 * bf16_lo_f32(w3.x);
        a1 += v0 * bf16_hi_f32(w0.x) + v1 * bf16_hi_f32(w1.x)
            + v2 * bf16_hi_f32(w2.x) + v3 * bf16_hi_f32(w3.x);
        a2 += v0 * bf16_lo_f32(w0.y) + v1 * bf16_lo_f32(w1.y)
            + v2 * bf16_lo_f32(w2.y) + v3 * bf16_lo_f32(w3.y);
        a3 += v0 * bf16_hi_f32(w0.y) + v1 * bf16_hi_f32(w1.y)
            + v2 * bf16_hi_f32(w2.y) + v3 * bf16_hi_f32(w3.y);
        a4 += v0 * bf16_lo_f32(w0.z) + v1 * bf16_lo_f32(w1.z)
            + v2 * bf16_lo_f32(w2.z) + v3 * bf16_lo_f32(w3.z);
        a5 += v0 * bf16_hi_f32(w0.z) + v1 * bf16_hi_f32(w1.z)
            + v2 * bf16_hi_f32(w2.z) + v3 * bf16_hi_f32(w3.z);
        a6 += v0 * bf16_lo_f32(w0.w) + v1 * bf16_lo_f32(w1.w)
            + v2 * bf16_lo_f32(w2.w) + v3 * bf16_lo_f32(w3.w);
        a7 += v0 * bf16_hi_f32(w0.w) + v1 * bf16_hi_f32(w1.w)
            + v2 * bf16_hi_f32(w2.w) + v3 * bf16_hi_f32(w3.w);
        k += 4;
    }

    if (sl < 13) {
        float* zp = Z + (long long)r * OUTPUT_DIM + i * HIDDEN + sl * 8;
        float4 o0;
        o0.x = a0 > 0.f ? a0 : 0.f;
        o0.y = a1 > 0.f ? a1 : 0.f;
        o0.z = a2 > 0.f ? a2 : 0.f;
        o0.w = a3 > 0.f ? a3 : 0.f;
        *(float4*)zp = o0;                       // cols 8*sl .. +3
        if (sl < 12) {
            float4 o1;
            o1.x = a4 > 0.f ? a4 : 0.f;
            o1.y = a5 > 0.f ? a5 : 0.f;
            o1.z = a6 > 0.f ? a6 : 0.f;
            o1.w = a7 > 0.f ? a7 : 0.f;
            *(float4*)(zp + 4) = o1;             // cols 8*sl+4 .. +7
        }
    }
}

// ---------------------------------------------------------------------------
// Fallback path: f32 GEMM + COO atomic scatter (only if ws too small)
// ---------------------------------------------------------------------------
#define TM 64
#define TN 64
#define TK 16

__global__ __launch_bounds__(256) void gemm_f32(
    const float* __restrict__ A, const float* __restrict__ B,
    float* __restrict__ C, int M, int N, int K, int ldc)
{
    __shared__ float Asl[TK][TM + 4];
    __shared__ float Bsl[TK][TN + 4];
    const int tid = threadIdx.x;
    const int tx  = tid & 15;
    const int ty  = tid >> 4;
    const int row0 = blockIdx.x * TM;
    const int col0 = blockIdx.y * TN;
    float acc[4][4] = {};
    for (int k0 = 0; k0 < K; k0 += TK) {
        #pragma unroll
        for (int it = 0; it < (TM * TK) / 256; ++it) {
            int idx = tid + it * 256;
            int m = idx >> 4, kk = idx & 15, gr = row0 + m;
            Asl[kk][m] = (gr < M) ? A[(long long)gr * K + (k0 + kk)] : 0.f;
        }
        #pragma unroll
        for (int it = 0; it < (TK * TN) / 256; ++it) {
            int idx = tid + it * 256;
            int kk = idx >> 6, n = idx & 63, gc = col0 + n;
            Bsl[kk][n] = (gc < N) ? B[(long long)(k0 + kk) * N + gc] : 0.f;
        }
        __syncthreads();
        #pragma unroll
        for (int kk = 0; kk < TK; ++kk) {
            float a[4], b[4];
            #pragma unroll
            for (int u = 0; u < 4; ++u) a[u] = Asl[kk][ty * 4 + u];
            #pragma unroll
            for (int v = 0; v < 4; ++v) b[v] = Bsl[kk][tx * 4 + v];
            #pragma unroll
            for (int u = 0; u < 4; ++u)
                #pragma unroll
                for (int v = 0; v < 4; ++v)
                    acc[u][v] += a[u] * b[v];
        }
        __syncthreads();
    }
    #pragma unroll
    for (int u = 0; u < 4; ++u) {
        int gr = row0 + ty * 4 + u;
        if (gr >= M) continue;
        #pragma unroll
        for (int v = 0; v < 4; ++v) {
            int gc = col0 + tx * 4 + v;
            if (gc < N) C[(long long)gr * ldc + gc] = acc[u][v];
        }
    }
}

__global__ __launch_bounds__(256) void scatter_edges(
    const float* __restrict__ sup_vals,
    const int*   __restrict__ sup_rows,
    const int*   __restrict__ sup_cols,
    const float* __restrict__ XU, const float* __restrict__ XV,
    float* __restrict__ z_u, float* __restrict__ z_v)
{
    const unsigned t = blockIdx.x * 256u + threadIdx.x;
    const unsigned total = (unsigned)NEDGE * HIDDEN;
    if (t >= total) return;
    const unsigned j  = t % HIDDEN;
    const unsigned eg = t / HIDDEN;
    const unsigned i  = eg / NNZ;
    const float val = sup_vals[eg];
    const int   r   = sup_rows[eg];
    const int   c   = sup_cols[eg];
    const int   colOff = i * HIDDEN + j;
    atomicAdd(&z_u[(long long)r * OUTPUT_DIM + colOff],
              val * XV[(long long)c * NPAD + colOff]);
    atomicAdd(&z_v[(long long)c * OUTPUT_DIM + colOff],
              val * XU[(long long)r * NPAD + colOff]);
}

__global__ __launch_bounds__(256) void relu_inplace(float4* __restrict__ p, int n4)
{
    int t = blockIdx.x * 256 + threadIdx.x;
    if (t >= n4) return;
    float4 v = p[t];
    v.x = v.x > 0.f ? v.x : 0.f;
    v.y = v.y > 0.f ? v.y : 0.f;
    v.z = v.z > 0.f ? v.z : 0.f;
    v.w = v.w > 0.f ? v.w : 0.f;
    p[t] = v;
}

extern "C" void kernel_launch(void* const* d_in, const int* in_sizes, int n_in,
                              void* d_out, int out_size, void* d_ws, size_t ws_size,
                              hipStream_t stream)
{
    const float* x_u      = (const float*)d_in[0];
    const float* x_v      = (const float*)d_in[1];
    const float* W        = (const float*)d_in[2];
    const float* sup_vals = (const float*)d_in[3];
    const int*   sup_rows = (const int*)d_in[4];
    const int*   sup_cols = (const int*)d_in[5];

    float* z_u = (float*)d_out;
    float* z_v = z_u + (long long)NUM_USERS * OUTPUT_DIM;

    const long long NU = (long long)NUM_USERS * 512;   // bf16 input elems (25.6M)
    const long long NV = (long long)NUM_ITEMS * 512;   //  5.12M
    const long long PU = (long long)NUM_SUPPORT * NUM_USERS * HPAD;  // 32M
    const long long PV = (long long)NUM_SUPPORT * NUM_ITEMS * HPAD;  // 6.4M
    const int NRU = NUM_SUPPORT * NUM_USERS;  // 250000 keys (u side)
    const int NRV = NUM_SUPPORT * NUM_ITEMS;  //  50000 output keys (v side)

    // ---- full-path workspace layout (~141 MB) ----
    ushort_t* Xp_u  = (ushort_t*)d_ws;        // packed gemm out [5][50000][128]
    ushort_t* Xp_v  = Xp_u + PU;              // packed gemm out [5][10000][128]
    ushort_t* xu_in = Xp_v + PV;              // bf16(x_u); reused as scratch post-GEMM
    ushort_t* xv_in = xu_in + NU;             // bf16(x_v)
    ushort_t* WbT   = xv_in + NV;             // bf16 W^T padded [512][512]
    u32* row_ptr_u  = (u32*)(WbT + 512 * 512);     // [NRU+1]
    u32* col_ptr_v  = row_ptr_u + (NRU + 1);       // [NKEY_V2+1]
    u32* partials   = col_ptr_v + (NKEY_V2 + 1);   // [512]
    size_t need_full = ((char*)(partials + 512)) - ((char*)d_ws);

    // scratch aliases inside xu_in (only used AFTER both GEMMs consumed it):
    // buf_v 16MB + histm (combined, 1.73MB) + perm_u 16MB + perm_v 16MB
    //   = 49.7MB <= 51.2MB.   buf_u (16MB) lives in the z_u output region
    //   (dead until spmm_pack4<u> overwrites all of z_u at the end).
    uint2* buf_v    = (uint2*)xu_in;               // [NEDGE] phase-B staging (v)
    u32*   histm_u  = (u32*)(buf_v + NEDGE);       // [HISTM_U_ALIGN] (incl. zero pad)
    u32*   histm_v  = histm_u + HISTM_U_ALIGN;     // [HISTM_V_SZ]
    uint2* perm_u   = (uint2*)(histm_v + HISTM_V_SZ);   // [NEDGE] (val,gidx)
    uint2* perm_v   = perm_u + NEDGE;                   // [NEDGE]
    uint2* buf_u    = (uint2*)z_u;                 // [NEDGE] staging (u) in d_out

    dim3 blk(256);

    if (ws_size >= need_full) {
        // ---- dense projections (bf16 MFMA, packed epilogue) ----
        {
            int na4 = (int)(NU / 4), nb4 = (int)(NV / 4);
            cvt_bf16_2<<<(na4 + nb4 + 255) / 256, blk, 0, stream>>>(
                (const float4*)x_u, (const float4*)x_v,
                (ushort4*)xu_in, (ushort4*)xv_in, na4, nb4);
        }
        make_WbT<<<(512 * 512) / 256, blk, 0, stream>>>(W, WbT);
        gemm_mfma_bf16<<<dim3((NUM_USERS + BM - 1) / BM, 512 / BN), blk, 0, stream>>>(
            xu_in, WbT, Xp_u, NUM_USERS);
        gemm_mfma_bf16<<<dim3((NUM_ITEMS + BM - 1) / BM, 512 / BN), blk, 0, stream>>>(
            xv_in, WbT, Xp_v, NUM_ITEMS);

        // xu_in is now dead -> buf_v/histm/perm scratch is live.
        // ---- fused chunk histograms (reads rows+cols once) ----
        hist_uv<<<NCHUNK, blk, 0, stream>>>(sup_rows, sup_cols, histm_u, histm_v);

        // ---- combined exclusive scan over [histm_u | pad | histm_v] ----
        {
            int nb = (HISTM_TOT + 1023) / 1024;                 // 422 <= 512
            scan1<<<nb, blk, 0, stream>>>(histm_u, HISTM_TOT, partials);
            scan_partials<<<1, dim3(512), 0, stream>>>(partials, nb);
            scan_add<<<(HISTM_TOT + 255) / 256, blk, 0, stream>>>(
                histm_u, HISTM_TOT, partials);
        }

        // ---- fused partition (reads COO once, stages both sides) ----
        partition_uv<<<NCHUNK, blk, 0, stream>>>(
            sup_rows, sup_cols, sup_vals, histm_u, histm_v, buf_u, buf_v);

        // ---- fused bucket scatter (u blocks then v blocks) ----
        bucket_scatter_uv<<<NB_U + NB_V2, blk, 0, stream>>>(
            buf_u, histm_u, row_ptr_u, perm_u,
            buf_v, histm_v, col_ptr_v, perm_v);

        // ---- SpMM (fused ReLU), 4 keys per wave, unroll-4, XCD-swizzled ----
        spmm_pack4<NUM_USERS, 1><<<((NRU / 4) * 64) / 256, blk, 0, stream>>>(
            row_ptr_u, perm_u, Xp_v, z_u, NUM_ITEMS);
        spmm_pack4<NUM_ITEMS, 4><<<((NRV / 4) * 64) / 256, blk, 0, stream>>>(
            col_ptr_v, perm_v, Xp_u, z_v, NUM_USERS);
    } else {
        // ---- fallback: f32 GEMM + atomic scatter ----
        float* XU = (float*)d_ws;
        float* XV = XU + (long long)NUM_USERS * NPAD;
        gemm_f32<<<dim3((NUM_USERS + TM - 1) / TM, (OUTPUT_DIM + TN - 1) / TN),
                   blk, 0, stream>>>(x_u, W, XU, NUM_USERS, OUTPUT_DIM, INPUT_DIM, NPAD);
        gemm_f32<<<dim3((NUM_ITEMS + TM - 1) / TM, (OUTPUT_DIM + TN - 1) / TN),
                   blk, 0, stream>>>(x_v, W, XV, NUM_ITEMS, OUTPUT_DIM, INPUT_DIM, NPAD);
        hipMemsetAsync(d_out, 0, (size_t)out_size * sizeof(float), stream);
        unsigned total = (unsigned)NEDGE * HIDDEN;
        scatter_edges<<<(total + 255u) / 256u, blk, 0, stream>>>(
            sup_vals, sup_rows, sup_cols, XU, XV, z_u, z_v);
        int n4 = out_size / 4;
        relu_inplace<<<(n4 + 255) / 256, blk, 0, stream>>>((float4*)d_out, n4);
    }
}

// Round 7
// 508.994 us; speedup vs baseline: 2.3613x; 1.0092x over previous
//
#include <hip/hip_runtime.h>

// Problem constants (match reference)
#define NUM_USERS   50000
#define NUM_ITEMS   10000
#define NUM_SUPPORT 5
#define INPUT_DIM   512      // K
#define OUTPUT_DIM  500
#define NPAD        512      // padded output-dim stride (fallback path only)
#define HIDDEN      100      // OUTPUT_DIM / NUM_SUPPORT
#define HPAD        128      // packed per-support row: 100 bf16 padded to 128 (256B)
#define NNZ         400000
#define NEDGE       (NUM_SUPPORT * NNZ)     // 2,000,000

// radix-partition parameters
#define CH_E        8192                         // edges per chunk
#define NCHUNK      ((NEDGE + CH_E - 1) / CH_E)  // 245
#define NB_U        ((NUM_SUPPORT * NUM_USERS + 255) / 256)   // 977
// v-side key space, rb-MAJOR: knew = (i*4 + rb)*NUM_ITEMS + col, rb=r/12500
// -> all concurrent waves touch the same 3.2MB user-slab at a time.
#define NKEY_V2     (NUM_SUPPORT * 4 * NUM_ITEMS)            // 200000
#define NB_V2       ((NKEY_V2 + 255) / 256)                  // 782
#define HISTM_U_SZ  (NB_U * NCHUNK)              // 239365
#define HISTM_U_ALIGN 239616                     // 234*1024: pad so v region is block-aligned
#define HISTM_V_SZ  (NB_V2 * NCHUNK)             // 191590
#define HISTM_TOT   (HISTM_U_ALIGN + HISTM_V_SZ) // 431206 (combined scan length)

typedef unsigned int u32;
typedef unsigned short ushort_t;
typedef __attribute__((ext_vector_type(4))) float f32x4;
typedef __attribute__((ext_vector_type(8))) short bf16x8;   // 8 bf16 in 4 VGPRs

// async global->LDS, 16B per lane. LDS side must be wave-uniform base + lane*16.
#define GLDS(g, l) __builtin_amdgcn_global_load_lds( \
    (const __attribute__((address_space(1))) unsigned int*)(g), \
    (__attribute__((address_space(3))) unsigned int*)(l), 16, 0, 0)

__device__ inline ushort_t bf16_rne(float f) {
    u32 u = __float_as_uint(f);
    u32 r = (u + 0x7FFFu + ((u >> 16) & 1u)) >> 16;
    return (ushort_t)r;
}
__device__ inline float bf16_lo_f32(u32 w) { return __uint_as_float(w << 16); }
__device__ inline float bf16_hi_f32(u32 w) { return __uint_as_float(w & 0xFFFF0000u); }

// rblock of a user id (4 blocks of 12500 -> 3.2MB gather slabs)
__device__ inline u32 rb3(u32 r) {
    return (r >= 12500u ? 1u : 0u) + (r >= 25000u ? 1u : 0u) + (r >= 37500u ? 1u : 0u);
}
// v-side sort key, rb-major within support
__device__ inline u32 vkey(u32 i, u32 col, u32 r) {
    return (i * 4u + rb3(r)) * (u32)NUM_ITEMS + col;
}

// bijective XCD-aware block swizzle (m204 form): each XCD gets a contiguous chunk
__device__ inline int xcd_swizzle(int bid, int nwg) {
    int q = nwg >> 3, rmd = nwg & 7;
    int xcd = bid & 7, idx = bid >> 3;
    int base = (xcd < rmd) ? xcd * (q + 1) : rmd * (q + 1) + (xcd - rmd) * q;
    return base + idx;
}

// ---------------------------------------------------------------------------
// f32 -> bf16 conversion (both tensors) + WbT transpose, one launch
// ---------------------------------------------------------------------------
__global__ __launch_bounds__(256) void cvt_all(
    const float4* __restrict__ a, const float4* __restrict__ b,
    const float* __restrict__ W,
    ushort4* __restrict__ oa, ushort4* __restrict__ ob,
    ushort_t* __restrict__ WbT, int na4, int nb4)
{
    int t = blockIdx.x * 256 + threadIdx.x;
    if (t < na4) {
        float4 v = a[t];
        ushort4 o;
        o.x = bf16_rne(v.x); o.y = bf16_rne(v.y);
        o.z = bf16_rne(v.z); o.w = bf16_rne(v.w);
        oa[t] = o;
        return;
    }
    int t2 = t - na4;
    if (t2 < nb4) {
        float4 v = b[t2];
        ushort4 o;
        o.x = bf16_rne(v.x); o.y = bf16_rne(v.y);
        o.z = bf16_rne(v.z); o.w = bf16_rne(v.w);
        ob[t2] = o;
        return;
    }
    int t3 = t2 - nb4;
    if (t3 < 512 * 512) {
        int n = t3 >> 9, k = t3 & 511;
        float v = (n < OUTPUT_DIM) ? W[k * OUTPUT_DIM + n] : 0.f;
        WbT[t3] = bf16_rne(v);
    }
}

// ---------------------------------------------------------------------------
// MFMA bf16 GEMM: Xp[seg][M][128](bf16) = packed A @ BT^T
// 128x128 tile, BK=32, 256 thr (4 waves, each 64x64 = 4x4 tiles of 16x16x32).
// Grid: x = n-tile (4), y = m-tile -> the 4 N-blocks sharing an A-row-block
// are launch-adjacent (A reuse stays in cache).
// Epilogue writes support-major packed layout: col c -> seg=c/100, off=c%100.
// ---------------------------------------------------------------------------
#define BM 128
#define BN 128
#define BK 32

__global__ __launch_bounds__(256) void gemm_mfma_bf16(
    const ushort_t* __restrict__ A,    // [M][512] bf16
    const ushort_t* __restrict__ BT,   // [512][512] bf16 (BT[n][k])
    ushort_t* __restrict__ Xp,         // [5][M][HPAD] bf16 packed
    int M)
{
    const int K = INPUT_DIM;
    __shared__ ushort_t As[BM * BK];   // [m][k], 64B rows
    __shared__ ushort_t Bs[BN * BK];   // [n][k], 64B rows

    const int tid  = threadIdx.x;
    const int wave = tid >> 6;
    const int lane = tid & 63;
    const int quad = lane >> 4;
    const int lr   = lane & 15;
    const int m0 = blockIdx.y * BM;
    const int n0 = blockIdx.x * BN;
    const int wm = (wave >> 1) * 64;
    const int wn = (wave & 1) * 64;

    f32x4 acc[4][4] = {};

    for (int k0 = 0; k0 < K; k0 += BK) {
        #pragma unroll
        for (int h = 0; h < 2; ++h) {
            int o   = tid * 16 + h * 4096;
            int row = o >> 6;
            int byt = o & 63;
            int gr  = m0 + row; if (gr >= M) gr = M - 1;   // clamp (masked at store)
            GLDS((const char*)A + ((long long)gr * K + k0) * 2 + byt, (char*)As + o);
        }
        #pragma unroll
        for (int h = 0; h < 2; ++h) {
            int o   = tid * 16 + h * 4096;
            int row = o >> 6;
            int byt = o & 63;
            GLDS((const char*)BT + ((long long)(n0 + row) * K + k0) * 2 + byt, (char*)Bs + o);
        }
        asm volatile("s_waitcnt vmcnt(0)" ::: "memory");
        __syncthreads();

        bf16x8 af[4], bfr[4];
        #pragma unroll
        for (int tm = 0; tm < 4; ++tm)
            af[tm] = *(const bf16x8*)(As + (wm + tm * 16 + lr) * BK + quad * 8);
        #pragma unroll
        for (int tn = 0; tn < 4; ++tn)
            bfr[tn] = *(const bf16x8*)(Bs + (wn + tn * 16 + lr) * BK + quad * 8);
        #pragma unroll
        for (int tm = 0; tm < 4; ++tm)
            #pragma unroll
            for (int tn = 0; tn < 4; ++tn)
                acc[tm][tn] = __builtin_amdgcn_mfma_f32_16x16x32_bf16(
                    af[tm], bfr[tn], acc[tm][tn], 0, 0, 0);
        __syncthreads();
    }

    // epilogue: C/D layout col=lane&15, row=quad*4+reg; scatter into packed Xp
    #pragma unroll
    for (int tm = 0; tm < 4; ++tm) {
        int rbase = m0 + wm + tm * 16 + quad * 4;
        #pragma unroll
        for (int tn = 0; tn < 4; ++tn) {
            int col = n0 + wn + tn * 16 + lr;
            if (col >= OUTPUT_DIM) continue;
            int seg = col / HIDDEN;             // const-div -> magic mul
            int off = col - seg * HIDDEN;
            ushort_t* dst = Xp + (long long)seg * M * HPAD + off;
            #pragma unroll
            for (int g = 0; g < 4; ++g) {
                int row = rbase + g;
                if (row < M) dst[(long long)row * HPAD] = bf16_rne(acc[tm][tn][g]);
            }
        }
    }
}

// ---------------------------------------------------------------------------
// Scan helpers. Combined u+v exclusive scan: data = [histm_u | pad0 | histm_v],
// length HISTM_TOT. v-region values include u's total (= NEDGE); scan_add
// subtracts it, so each side ends with its own exclusive offsets.
// ---------------------------------------------------------------------------
__global__ __launch_bounds__(256) void scan1(u32* __restrict__ data, int n,
                                             u32* __restrict__ partials)
{
    __shared__ u32 sh[256];
    int t = threadIdx.x;
    int base = blockIdx.x * 1024 + t * 4;
    u32 x[4];
    #pragma unroll
    for (int k = 0; k < 4; ++k) {
        int idx = base + k;
        x[k] = (idx < n) ? data[idx] : 0u;
    }
    u32 tsum = x[0] + x[1] + x[2] + x[3];
    sh[t] = tsum;
    __syncthreads();
    for (int off = 1; off < 256; off <<= 1) {
        u32 v = (t >= off) ? sh[t - off] : 0u;
        __syncthreads();
        sh[t] += v;
        __syncthreads();
    }
    u32 run = (t > 0) ? sh[t - 1] : 0u;
    if (t == 255) partials[blockIdx.x] = sh[255];
    #pragma unroll
    for (int k = 0; k < 4; ++k) {
        int idx = base + k;
        if (idx < n) data[idx] = run;
        run += x[k];
    }
}

__global__ __launch_bounds__(512) void scan_partials(u32* __restrict__ partials, int n)
{
    __shared__ u32 sh[512];
    int t = threadIdx.x;
    u32 x = (t < n) ? partials[t] : 0u;
    sh[t] = x;
    __syncthreads();
    for (int off = 1; off < 512; off <<= 1) {
        u32 v = (t >= off) ? sh[t - off] : 0u;
        __syncthreads();
        sh[t] += v;
        __syncthreads();
    }
    if (t < n) partials[t] = (t > 0) ? sh[t - 1] : 0u;
}

__global__ __launch_bounds__(256) void scan_add(u32* __restrict__ data, int n,
                                                const u32* __restrict__ partials)
{
    int idx = blockIdx.x * 256 + threadIdx.x;
    if (idx >= n) return;
    u32 adj = (idx >= HISTM_U_ALIGN) ? (u32)NEDGE : 0u;
    data[idx] = data[idx] + partials[idx >> 10] - adj;
}

// ---------------------------------------------------------------------------
// Chunked radix partition (no global atomics, no line-amplified scatter).
// u-side key: ku = i*NUM_USERS + row               (bucket = ku>>8)
// v-side key: knew = (i*4 + rb3(row))*NUM_ITEMS + col  (bucket = knew>>8)
// Payloads: u: (ku<<14)|col ; v: (kv16<<16)|row, kv16 = i*NUM_ITEMS+col
//   (knew recomputed from fields via const-div by NUM_ITEMS).
// ---------------------------------------------------------------------------
__global__ __launch_bounds__(256) void hist_uv(
    const int* __restrict__ rows, const int* __restrict__ cols,
    u32* __restrict__ histm_u, u32* __restrict__ histm_v)
{
    __shared__ u32 hu[NB_U];
    __shared__ u32 hv[NB_V2];
    const int tid = threadIdx.x;
    const int c = blockIdx.x;
    // zero the alignment pad between the two hist matrices (block 0 only)
    if (c == 0)
        for (int z = HISTM_U_SZ + tid; z < HISTM_U_ALIGN; z += 256) histm_u[z] = 0u;
    for (int b = tid; b < NB_U; b += 256) hu[b] = 0u;
    for (int b = tid; b < NB_V2; b += 256) hv[b] = 0u;
    __syncthreads();
    int base = c * CH_E;
    int end = base + CH_E; if (end > NEDGE) end = NEDGE;
    for (int e = base + tid; e < end; e += 256) {
        unsigned i = (unsigned)e / (unsigned)NNZ;
        u32 r = (u32)rows[e];
        u32 ku = i * (u32)NUM_USERS + r;
        u32 knew = vkey(i, (u32)cols[e], r);
        atomicAdd(&hu[ku >> 8], 1u);
        atomicAdd(&hv[knew >> 8], 1u);
    }
    __syncthreads();
    for (int b = tid; b < NB_U; b += 256) histm_u[b * NCHUNK + c] = hu[b];
    for (int b = tid; b < NB_V2; b += 256) histm_v[b * NCHUNK + c] = hv[b];
}

__global__ __launch_bounds__(256) void partition_uv(
    const int* __restrict__ rows, const int* __restrict__ cols,
    const float* __restrict__ vals,
    const u32* __restrict__ histm_u, const u32* __restrict__ histm_v,
    uint2* __restrict__ buf_u, uint2* __restrict__ buf_v)
{
    __shared__ u32 cu[NB_U];
    __shared__ u32 cv[NB_V2];
    const int tid = threadIdx.x;
    const int c = blockIdx.x;
    for (int b = tid; b < NB_U; b += 256) cu[b] = histm_u[b * NCHUNK + c];
    for (int b = tid; b < NB_V2; b += 256) cv[b] = histm_v[b * NCHUNK + c];
    __syncthreads();
    int base = c * CH_E;
    int end = base + CH_E; if (end > NEDGE) end = NEDGE;
    for (int e = base + tid; e < end; e += 256) {
        unsigned i = (unsigned)e / (unsigned)NNZ;
        u32 r = (u32)rows[e];
        u32 col = (u32)cols[e];
        u32 vb = __float_as_uint(vals[e]);
        u32 ku = i * (u32)NUM_USERS + r;
        u32 kv16 = i * (u32)NUM_ITEMS + col;
        u32 knew = vkey(i, col, r);
        u32 pu = atomicAdd(&cu[ku >> 8], 1u);
        uint2 eu; eu.x = vb; eu.y = (ku << 14) | col;
        buf_u[pu] = eu;
        u32 pv = atomicAdd(&cv[knew >> 8], 1u);
        uint2 ev; ev.x = vb; ev.y = (kv16 << 16) | r;
        buf_v[pv] = ev;
    }
}

__device__ inline void bucket_body_u(
    int b, const uint2* __restrict__ buf, const u32* __restrict__ histm,
    u32* __restrict__ ptr, uint2* __restrict__ perm,
    u32* cnt, u32* scn)
{
    constexpr int NKEY = NUM_SUPPORT * NUM_USERS;
    constexpr int NB = NB_U;
    const int tid = threadIdx.x;
    const u32 key0 = (u32)b << 8;
    const u32 start = histm[b * NCHUNK];
    const u32 bend  = (b + 1 < NB) ? histm[(b + 1) * NCHUNK] : (u32)NEDGE;
    if (b == 0 && tid == 0) ptr[NKEY] = (u32)NEDGE;   // CSR sentinel
    cnt[tid] = 0u;
    __syncthreads();
    for (u32 j = start + tid; j < bend; j += 256) {
        u32 key = buf[j].y >> 14;
        atomicAdd(&cnt[key - key0], 1u);
    }
    __syncthreads();
    scn[tid] = cnt[tid];
    __syncthreads();
    for (int off = 1; off < 256; off <<= 1) {
        u32 v = (tid >= off) ? scn[tid - off] : 0u;
        __syncthreads();
        scn[tid] += v;
        __syncthreads();
    }
    u32 myoff = start + scn[tid] - cnt[tid];
    if (key0 + (u32)tid < (u32)NKEY) ptr[key0 + tid] = myoff;
    __syncthreads();
    cnt[tid] = myoff;
    __syncthreads();
    for (u32 j = start + tid; j < bend; j += 256) {
        uint2 q = buf[j];
        u32 key = q.y >> 14;
        u32 p = atomicAdd(&cnt[key - key0], 1u);
        uint2 out;
        out.x = q.x;
        out.y = q.y & 0x3FFFu;
        perm[p] = out;
    }
}

__device__ inline void bucket_body_v(
    int b, const uint2* __restrict__ buf, const u32* __restrict__ histm,
    u32* __restrict__ ptr, uint2* __restrict__ perm,
    u32* cnt, u32* scn)
{
    constexpr int NKEY = NKEY_V2;
    constexpr int NB = NB_V2;
    const int tid = threadIdx.x;
    const u32 key0 = (u32)b << 8;
    const u32 start = histm[b * NCHUNK];
    const u32 bend  = (b + 1 < NB) ? histm[(b + 1) * NCHUNK] : (u32)NEDGE;
    if (b == 0 && tid == 0) ptr[NKEY] = (u32)NEDGE;   // CSR sentinel
    cnt[tid] = 0u;
    __syncthreads();
    for (u32 j = start + tid; j < bend; j += 256) {
        u32 y = buf[j].y;
        u32 kv16 = y >> 16;
        u32 i = kv16 / (u32)NUM_ITEMS;
        u32 col = kv16 - i * (u32)NUM_ITEMS;
        u32 key = vkey(i, col, y & 0xFFFFu);
        atomicAdd(&cnt[key - key0], 1u);
    }
    __syncthreads();
    scn[tid] = cnt[tid];
    __syncthreads();
    for (int off = 1; off < 256; off <<= 1) {
        u32 v = (tid >= off) ? scn[tid - off] : 0u;
        __syncthreads();
        scn[tid] += v;
        __syncthreads();
    }
    u32 myoff = start + scn[tid] - cnt[tid];
    if (key0 + (u32)tid < (u32)NKEY) ptr[key0 + tid] = myoff;
    __syncthreads();
    cnt[tid] = myoff;
    __syncthreads();
    for (u32 j = start + tid; j < bend; j += 256) {
        uint2 q = buf[j];
        u32 kv16 = q.y >> 16;
        u32 i = kv16 / (u32)NUM_ITEMS;
        u32 col = kv16 - i * (u32)NUM_ITEMS;
        u32 key = vkey(i, col, q.y & 0xFFFFu);
        u32 p = atomicAdd(&cnt[key - key0], 1u);
        uint2 out;
        out.x = q.x;
        out.y = q.y & 0xFFFFu;
        perm[p] = out;
    }
}

__global__ __launch_bounds__(256) void bucket_scatter_uv(
    const uint2* __restrict__ buf_u, const u32* __restrict__ histm_u,
    u32* __restrict__ ptr_u, uint2* __restrict__ perm_u,
    const uint2* __restrict__ buf_v, const u32* __restrict__ histm_v,
    u32* __restrict__ ptr_v, uint2* __restrict__ perm_v)
{
    __shared__ u32 cnt[256];
    __shared__ u32 scn[256];
    if (blockIdx.x < NB_U)
        bucket_body_u(blockIdx.x, buf_u, histm_u, ptr_u, perm_u, cnt, scn);
    else
        bucket_body_v(blockIdx.x - NB_U, buf_v, histm_v, ptr_v, perm_v, cnt, scn);
}

// ---------------------------------------------------------------------------
// Packed SpMM, 4 output keys per wave: each 16-lane group owns one output key
// (support i, row/col c) and iterates its RBN runs ptr[(i*RBN+rb)*NROWS+c].
// Unroll-4 -> 16 row-gathers in flight per wave. Each lane gathers 16B
// (8 bf16 cols) of the 256B packed row; lanes hold the final accumulators
// directly. Fused ReLU; per group, lanes 0..12 write the 100 f32.
// u and v sides run in ONE launch (block-range split, tail overlap).
// ---------------------------------------------------------------------------
template<int NROWS, int RBN>
__device__ inline void spmm_body(
    int bid, int nwg,
    const u32* __restrict__ ptr,      // [5*NROWS*RBN + 1] CSR offsets
    const uint2* __restrict__ perm,   // [NEDGE] (val_bits, gather_idx)
    const ushort_t* __restrict__ Xp,  // [5][nsrc][HPAD] bf16 packed
    float* __restrict__ Z,            // [NROWS][OUTPUT_DIM] f32
    int nsrc)
{
    bid = xcd_swizzle(bid, nwg);
    int w = bid * 4 + (int)(threadIdx.x >> 6);
    w = __builtin_amdgcn_readfirstlane(w);
    const int lane = threadIdx.x & 63;
    const int g  = lane >> 4;     // group 0..3 -> key w*4+g
    const int sl = lane & 15;     // 8 bf16 cols per lane

    int key = w * 4 + g;          // < 5*NROWS (divisible by 4)
    int i = key / NROWS;          // support segment
    int c = key - i * NROWS;      // output row

    const ushort_t* Xs = Xp + (long long)i * nsrc * HPAD + sl * 8;

    float a0 = 0.f, a1 = 0.f, a2 = 0.f, a3 = 0.f;
    float a4 = 0.f, a5 = 0.f, a6 = 0.f, a7 = 0.f;

    #pragma unroll
    for (int rb = 0; rb < RBN; ++rb) {
        int kk = (i * RBN + rb) * NROWS + c;
        u32 s = ptr[kk];
        u32 e = ptr[kk + 1];
        // wave-max trip count (groups differ only in lane bits 4..5)
        u32 m = e - s;
        { u32 t = (u32)__shfl_xor((int)m, 16); m = m > t ? m : t; }
        { u32 t = (u32)__shfl_xor((int)m, 32); m = m > t ? m : t; }
        int iters = (int)((m + 3) >> 2);
        u32 k = s;
        for (int it = 0; it < iters; ++it) {
            bool p0 = k < e, p1 = (k + 1) < e, p2 = (k + 2) < e, p3 = (k + 3) < e;
            u32 j0 = p0 ? k : 0u;
            u32 j1 = p1 ? (k + 1) : 0u;
            u32 j2 = p2 ? (k + 2) : 0u;
            u32 j3 = p3 ? (k + 3) : 0u;
            uint2 q0 = perm[j0], q1 = perm[j1], q2 = perm[j2], q3 = perm[j3];
            float v0 = p0 ? __uint_as_float(q0.x) : 0.f;
            float v1 = p1 ? __uint_as_float(q1.x) : 0.f;
            float v2 = p2 ? __uint_as_float(q2.x) : 0.f;
            float v3 = p3 ? __uint_as_float(q3.x) : 0.f;
            uint4 w0 = *(const uint4*)(Xs + ((long long)q0.y << 7));
            uint4 w1 = *(const uint4*)(Xs + ((long long)q1.y << 7));
            uint4 w2 = *(const uint4*)(Xs + ((long long)q2.y << 7));
            uint4 w3 = *(const uint4*)(Xs + ((long long)q3.y << 7));
            a0 += v0 * bf16_lo_f32(w0.x) + v1 * bf16_lo_f32(w1.x)
                + v2 * bf16_lo_f32(w2.x) + v3 * bf16_lo_f32(w3.x);
            a1 += v0 * bf16_hi_f32(w0.x) + v1 * bf16_hi_f32(w1.x)
                + v2 * bf16_hi_f32(w2.x) + v3 * bf16_hi_f32(w3.x);
            a2 += v0 * bf16_lo_f32(w0.y) + v1 * bf16_lo_f32(w1.y)
                + v2 * bf16_lo_f32(w2.y) + v3 * bf16_lo_f32(w3.y);
            a3 += v0 * bf16_hi_f32(w0.y) + v1 * bf16_hi_f32(w1.y)
                + v2 * bf16_hi_f32(w2.y) + v3 * bf16_hi_f32(w3.y);
            a4 += v0 * bf16_lo_f32(w0.z) + v1 * bf16_lo_f32(w1.z)
                + v2 * bf16_lo_f32(w2.z) + v3 * bf16_lo_f32(w3.z);
            a5 += v0 * bf16_hi_f32(w0.z) + v1 * bf16_hi_f32(w1.z)
                + v2 * bf16_hi_f32(w2.z) + v3 * bf16_hi_f32(w3.z);
            a6 += v0 * bf16_lo_f32(w0.w) + v1 * bf16_lo_f32(w1.w)
                + v2 * bf16_lo_f32(w2.w) + v3 * bf16_lo_f32(w3.w);
            a7 += v0 * bf16_hi_f32(w0.w) + v1 * bf16_hi_f32(w1.w)
                + v2 * bf16_hi_f32(w2.w) + v3 * bf16_hi_f32(w3.w);
            k += 4;
        }
    }

    if (sl < 13) {
        float* zp = Z + (long long)c * OUTPUT_DIM + i * HIDDEN + sl * 8;
        float4 o0;
        o0.x = a0 > 0.f ? a0 : 0.f;
        o0.y = a1 > 0.f ? a1 : 0.f;
        o0.z = a2 > 0.f ? a2 : 0.f;
        o0.w = a3 > 0.f ? a3 : 0.f;
        *(float4*)zp = o0;                       // cols 8*sl .. +3
        if (sl < 12) {
            float4 o1;
            o1.x = a4 > 0.f ? a4 : 0.f;
            o1.y = a5 > 0.f ? a5 : 0.f;
            o1.z = a6 > 0.f ? a6 : 0.f;
            o1.w = a7 > 0.f ? a7 : 0.f;
            *(float4*)(zp + 4) = o1;             // cols 8*sl+4 .. +7
        }
    }
}

#define NBU4 ((NUM_SUPPORT * NUM_USERS) / 16)   // 15625 blocks (u portion)
#define NBV4 ((NUM_SUPPORT * NUM_ITEMS) / 16)   //  3125 blocks (v portion)

__global__ __launch_bounds__(256) void spmm_both(
    const u32* __restrict__ ptr_u, const uint2* __restrict__ perm_u,
    const ushort_t* __restrict__ Xp_v, float* __restrict__ z_u,
    const u32* __restrict__ ptr_v, const uint2* __restrict__ perm_v,
    const ushort_t* __restrict__ Xp_u, float* __restrict__ z_v)
{
    if ((int)blockIdx.x < NBU4)
        spmm_body<NUM_USERS, 1>(blockIdx.x, NBU4, ptr_u, perm_u, Xp_v, z_u, NUM_ITEMS);
    else
        spmm_body<NUM_ITEMS, 4>(blockIdx.x - NBU4, NBV4, ptr_v, perm_v, Xp_u, z_v, NUM_USERS);
}

// ---------------------------------------------------------------------------
// Fallback path: f32 GEMM + COO atomic scatter (only if ws too small)
// ---------------------------------------------------------------------------
#define TM 64
#define TN 64
#define TK 16

__global__ __launch_bounds__(256) void gemm_f32(
    const float* __restrict__ A, const float* __restrict__ B,
    float* __restrict__ C, int M, int N, int K, int ldc)
{
    __shared__ float Asl[TK][TM + 4];
    __shared__ float Bsl[TK][TN + 4];
    const int tid = threadIdx.x;
    const int tx  = tid & 15;
    const int ty  = tid >> 4;
    const int row0 = blockIdx.x * TM;
    const int col0 = blockIdx.y * TN;
    float acc[4][4] = {};
    for (int k0 = 0; k0 < K; k0 += TK) {
        #pragma unroll
        for (int it = 0; it < (TM * TK) / 256; ++it) {
            int idx = tid + it * 256;
            int m = idx >> 4, kk = idx & 15, gr = row0 + m;
            Asl[kk][m] = (gr < M) ? A[(long long)gr * K + (k0 + kk)] : 0.f;
        }
        #pragma unroll
        for (int it = 0; it < (TK * TN) / 256; ++it) {
            int idx = tid + it * 256;
            int kk = idx >> 6, n = idx & 63, gc = col0 + n;
            Bsl[kk][n] = (gc < N) ? B[(long long)(k0 + kk) * N + gc] : 0.f;
        }
        __syncthreads();
        #pragma unroll
        for (int kk = 0; kk < TK; ++kk) {
            float a[4], b[4];
            #pragma unroll
            for (int u = 0; u < 4; ++u) a[u] = Asl[kk][ty * 4 + u];
            #pragma unroll
            for (int v = 0; v < 4; ++v) b[v] = Bsl[kk][tx * 4 + v];
            #pragma unroll
            for (int u = 0; u < 4; ++u)
                #pragma unroll
                for (int v = 0; v < 4; ++v)
                    acc[u][v] += a[u] * b[v];
        }
        __syncthreads();
    }
    #pragma unroll
    for (int u = 0; u < 4; ++u) {
        int gr = row0 + ty * 4 + u;
        if (gr >= M) continue;
        #pragma unroll
        for (int v = 0; v < 4; ++v) {
            int gc = col0 + tx * 4 + v;
            if (gc < N) C[(long long)gr * ldc + gc] = acc[u][v];
        }
    }
}

__global__ __launch_bounds__(256) void scatter_edges(
    const float* __restrict__ sup_vals,
    const int*   __restrict__ sup_rows,
    const int*   __restrict__ sup_cols,
    const float* __restrict__ XU, const float* __restrict__ XV,
    float* __restrict__ z_u, float* __restrict__ z_v)
{
    const unsigned t = blockIdx.x * 256u + threadIdx.x;
    const unsigned total = (unsigned)NEDGE * HIDDEN;
    if (t >= total) return;
    const unsigned j  = t % HIDDEN;
    const unsigned eg = t / HIDDEN;
    const unsigned i  = eg / NNZ;
    const float val = sup_vals[eg];
    const int   r   = sup_rows[eg];
    const int   c   = sup_cols[eg];
    const int   colOff = i * HIDDEN + j;
    atomicAdd(&z_u[(long long)r * OUTPUT_DIM + colOff],
              val * XV[(long long)c * NPAD + colOff]);
    atomicAdd(&z_v[(long long)c * OUTPUT_DIM + colOff],
              val * XU[(long long)r * NPAD + colOff]);
}

__global__ __launch_bounds__(256) void relu_inplace(float4* __restrict__ p, int n4)
{
    int t = blockIdx.x * 256 + threadIdx.x;
    if (t >= n4) return;
    float4 v = p[t];
    v.x = v.x > 0.f ? v.x : 0.f;
    v.y = v.y > 0.f ? v.y : 0.f;
    v.z = v.z > 0.f ? v.z : 0.f;
    v.w = v.w > 0.f ? v.w : 0.f;
    p[t] = v;
}

extern "C" void kernel_launch(void* const* d_in, const int* in_sizes, int n_in,
                              void* d_out, int out_size, void* d_ws, size_t ws_size,
                              hipStream_t stream)
{
    const float* x_u      = (const float*)d_in[0];
    const float* x_v      = (const float*)d_in[1];
    const float* W        = (const float*)d_in[2];
    const float* sup_vals = (const float*)d_in[3];
    const int*   sup_rows = (const int*)d_in[4];
    const int*   sup_cols = (const int*)d_in[5];

    float* z_u = (float*)d_out;
    float* z_v = z_u + (long long)NUM_USERS * OUTPUT_DIM;

    const long long NU = (long long)NUM_USERS * 512;   // bf16 input elems (25.6M)
    const long long NV = (long long)NUM_ITEMS * 512;   //  5.12M
    const long long PU = (long long)NUM_SUPPORT * NUM_USERS * HPAD;  // 32M
    const long long PV = (long long)NUM_SUPPORT * NUM_ITEMS * HPAD;  // 6.4M
    const int NRU = NUM_SUPPORT * NUM_USERS;  // 250000 keys (u side)
    const int NRV = NUM_SUPPORT * NUM_ITEMS;  //  50000 output keys (v side)

    // ---- full-path workspace layout (~141 MB) ----
    ushort_t* Xp_u  = (ushort_t*)d_ws;        // packed gemm out [5][50000][128]
    ushort_t* Xp_v  = Xp_u + PU;              // packed gemm out [5][10000][128]
    ushort_t* xu_in = Xp_v + PV;              // bf16(x_u); reused as scratch post-GEMM
    ushort_t* xv_in = xu_in + NU;             // bf16(x_v)
    ushort_t* WbT   = xv_in + NV;             // bf16 W^T padded [512][512]
    u32* row_ptr_u  = (u32*)(WbT + 512 * 512);     // [NRU+1]
    u32* col_ptr_v  = row_ptr_u + (NRU + 1);       // [NKEY_V2+1]
    u32* partials   = col_ptr_v + (NKEY_V2 + 1);   // [512]
    size_t need_full = ((char*)(partials + 512)) - ((char*)d_ws);

    // scratch aliases inside xu_in (only used AFTER both GEMMs consumed it):
    // buf_v 16MB + histm (combined, 1.73MB) + perm_u 16MB + perm_v 16MB
    //   = 49.7MB <= 51.2MB.   buf_u (16MB) lives in the z_u output region
    //   (dead until spmm_both overwrites all of z_u at the end).
    uint2* buf_v    = (uint2*)xu_in;               // [NEDGE] phase-B staging (v)
    u32*   histm_u  = (u32*)(buf_v + NEDGE);       // [HISTM_U_ALIGN] (incl. zero pad)
    u32*   histm_v  = histm_u + HISTM_U_ALIGN;     // [HISTM_V_SZ]
    uint2* perm_u   = (uint2*)(histm_v + HISTM_V_SZ);   // [NEDGE] (val,gidx)
    uint2* perm_v   = perm_u + NEDGE;                   // [NEDGE]
    uint2* buf_u    = (uint2*)z_u;                 // [NEDGE] staging (u) in d_out

    dim3 blk(256);

    if (ws_size >= need_full) {
        // ---- dense projections (bf16 MFMA, packed epilogue) ----
        {
            int na4 = (int)(NU / 4), nb4 = (int)(NV / 4);
            int tot = na4 + nb4 + 512 * 512;
            cvt_all<<<(tot + 255) / 256, blk, 0, stream>>>(
                (const float4*)x_u, (const float4*)x_v, W,
                (ushort4*)xu_in, (ushort4*)xv_in, WbT, na4, nb4);
        }
        gemm_mfma_bf16<<<dim3(512 / BN, (NUM_USERS + BM - 1) / BM), blk, 0, stream>>>(
            xu_in, WbT, Xp_u, NUM_USERS);
        gemm_mfma_bf16<<<dim3(512 / BN, (NUM_ITEMS + BM - 1) / BM), blk, 0, stream>>>(
            xv_in, WbT, Xp_v, NUM_ITEMS);

        // xu_in is now dead -> buf_v/histm/perm scratch is live.
        // ---- fused chunk histograms (reads rows+cols once) ----
        hist_uv<<<NCHUNK, blk, 0, stream>>>(sup_rows, sup_cols, histm_u, histm_v);

        // ---- combined exclusive scan over [histm_u | pad | histm_v] ----
        {
            int nb = (HISTM_TOT + 1023) / 1024;                 // 422 <= 512
            scan1<<<nb, blk, 0, stream>>>(histm_u, HISTM_TOT, partials);
            scan_partials<<<1, dim3(512), 0, stream>>>(partials, nb);
            scan_add<<<(HISTM_TOT + 255) / 256, blk, 0, stream>>>(
                histm_u, HISTM_TOT, partials);
        }

        // ---- fused partition (reads COO once, stages both sides) ----
        partition_uv<<<NCHUNK, blk, 0, stream>>>(
            sup_rows, sup_cols, sup_vals, histm_u, histm_v, buf_u, buf_v);

        // ---- fused bucket scatter (u blocks then v blocks) ----
        bucket_scatter_uv<<<NB_U + NB_V2, blk, 0, stream>>>(
            buf_u, histm_u, row_ptr_u, perm_u,
            buf_v, histm_v, col_ptr_v, perm_v);

        // ---- SpMM (fused ReLU), both sides in one launch ----
        spmm_both<<<NBU4 + NBV4, blk, 0, stream>>>(
            row_ptr_u, perm_u, Xp_v, z_u,
            col_ptr_v, perm_v, Xp_u, z_v);
    } else {
        // ---- fallback: f32 GEMM + atomic scatter ----
        float* XU = (float*)d_ws;
        float* XV = XU + (long long)NUM_USERS * NPAD;
        gemm_f32<<<dim3((NUM_USERS + TM - 1) / TM, (OUTPUT_DIM + TN - 1) / TN),
                   blk, 0, stream>>>(x_u, W, XU, NUM_USERS, OUTPUT_DIM, INPUT_DIM, NPAD);
        gemm_f32<<<dim3((NUM_ITEMS + TM - 1) / TM, (OUTPUT_DIM + TN - 1) / TN),
                   blk, 0, stream>>>(x_v, W, XV, NUM_ITEMS, OUTPUT_DIM, INPUT_DIM, NPAD);
        hipMemsetAsync(d_out, 0, (size_t)out_size * sizeof(float), stream);
        unsigned total = (unsigned)NEDGE * HIDDEN;
        scatter_edges<<<(total + 255u) / 256u, blk, 0, stream>>>(
            sup_vals, sup_rows, sup_cols, XU, XV, z_u, z_v);
        int n4 = out_size / 4;
        relu_inplace<<<(n4 + 255) / 256, blk, 0, stream>>>((float4*)d_out, n4);
    }
}